// Round 1
// baseline (3128.682 us; speedup 1.0000x reference)
//
#include <hip/hip_runtime.h>
#include <math.h>

#define NA 100000
#define NB 100000
#define NROW 100000   // all four relations have 100000 output rows
#define FT 128
#define H1 128
#define H2 64
#define OUTD 64
#define SCHUNK 4096   // elements per scan block

// ---------------- zero fill (used for CSR count arrays) ----------------
__global__ __launch_bounds__(256) void zero_k(float4* __restrict__ p, int n4) {
    int i = blockIdx.x * 256 + threadIdx.x;
    if (i < n4) p[i] = make_float4(0.f, 0.f, 0.f, 0.f);
}

// ---------------- CSR build: histogram ----------------
__global__ __launch_bounds__(256) void hist_k(const int* __restrict__ rows,
                                              int* __restrict__ cnt, int E) {
    int i = blockIdx.x * 256 + threadIdx.x;
    if (i < E) atomicAdd(&cnt[rows[i]], 1);
}

// ---------------- multi-block segmented exclusive scan ----------------
// phase 1: per-block sums (grid = 4 * bpr)
__global__ __launch_bounds__(256) void scan1_k(const int* __restrict__ cnt4,
                                               int* __restrict__ bsum, int N, int bpr) {
    const int r = blockIdx.x / bpr;
    const int b = blockIdx.x - r * bpr;
    const int* cnt = cnt4 + (size_t)r * N + (size_t)b * SCHUNK;
    const int count = min(SCHUNK, N - b * SCHUNK);
    const int t = threadIdx.x;
    int s = 0;
    for (int i = t; i < count; i += 256) s += cnt[i];
#pragma unroll
    for (int m = 1; m < 64; m <<= 1) s += __shfl_xor(s, m);
    __shared__ int sh[4];
    if ((t & 63) == 0) sh[t >> 6] = s;
    __syncthreads();
    if (t == 0) bsum[blockIdx.x] = sh[0] + sh[1] + sh[2] + sh[3];
}

// phase 2: exclusive scan of block sums, one wave per relation (bpr <= 64)
__global__ __launch_bounds__(256) void scan2_k(int* __restrict__ bsum, int bpr) {
    const int lane = threadIdx.x & 63;
    const int r = threadIdx.x >> 6;
    int v = (lane < bpr) ? bsum[r * bpr + lane] : 0;
    int inc = v;
#pragma unroll
    for (int m = 1; m < 64; m <<= 1) {
        int u = __shfl_up(inc, m);
        if (lane >= m) inc += u;
    }
    if (lane < bpr) bsum[r * bpr + lane] = inc - v;
}

// phase 3: per-block local scan + offset, write rp & cur (grid = 4 * bpr)
__global__ __launch_bounds__(256) void scan3_k(const int* __restrict__ cnt4,
                                               const int* __restrict__ bsum,
                                               int* __restrict__ rp4,
                                               int* __restrict__ cur4, int N, int bpr) {
    const int r = blockIdx.x / bpr;
    const int b = blockIdx.x - r * bpr;
    const int base0 = b * SCHUNK;
    const int* cnt = cnt4 + (size_t)r * N;
    int* rp  = rp4  + (size_t)r * (N + 1);
    int* cur = cur4 + (size_t)r * N;
    const int count = min(SCHUNK, N - base0);
    const int t = threadIdx.x;
    const int off = base0 + t * 16;

    int v[16];
    int tot = 0;
#pragma unroll
    for (int i = 0; i < 16; i++) {
        const int idx = off + i;
        v[i] = (idx < base0 + count) ? cnt[idx] : 0;
        tot += v[i];
    }
    // wave inclusive scan of per-thread totals
    int inc = tot;
#pragma unroll
    for (int m = 1; m < 64; m <<= 1) {
        int u = __shfl_up(inc, m);
        if ((t & 63) >= m) inc += u;
    }
    __shared__ int wsum[4];
    if ((t & 63) == 63) wsum[t >> 6] = inc;
    __syncthreads();
    int wbase = 0;
    const int w = t >> 6;
    for (int i = 0; i < 4; i++) if (i < w) wbase += wsum[i];

    int ex = inc - tot + wbase + bsum[blockIdx.x];
#pragma unroll
    for (int i = 0; i < 16; i++) {
        const int idx = off + i;
        if (idx < base0 + count) {
            rp[idx] = ex; cur[idx] = ex;
            ex += v[i];
        }
    }
    if (N - 1 >= off && N - 1 < off + 16) rp[N] = ex;
}

// ---------------- CSR build: scatter (col,val) packed int2 ----------------
// single 8B store per edge (was 2x 4B stores to separate arrays -> ~2x fewer
// dirty-line touches, less cross-XCD line bouncing)
__global__ __launch_bounds__(256) void scatter_k(const int* __restrict__ rows,
                                                 const int* __restrict__ cols,
                                                 const float* __restrict__ vals,
                                                 int* __restrict__ cur,
                                                 int2* __restrict__ edgesS, int E) {
    int i = blockIdx.x * 256 + threadIdx.x;
    if (i >= E) return;
    int r = rows[i];
    int pos = atomicAdd(&cur[r], 1);
    edgesS[pos] = make_int2(cols[i], __float_as_int(vals[i]));
}

// ---------------- SpMM (CSR gather), fused bias + LeakyReLU ----------------
// One wave per output row; 16 gathers kept in flight per chunk for latency
// hiding (dummy lanes gather row 0 with val=0: L1-resident, harmless).
template<int F>
__global__ __launch_bounds__(256) void spmm_csr_k(
    const int* __restrict__ rp, const int2* __restrict__ edges,
    const float* __restrict__ X,
    const float* __restrict__ bias, float* __restrict__ out, int N)
{
    const int wid  = (blockIdx.x * 256 + threadIdx.x) >> 6;
    const int lane = threadIdx.x & 63;
    if (wid >= N) return;
    const int s = rp[wid];
    const int e = rp[wid + 1];

    if (F == 128) {
        float ax = 0.f, ay = 0.f;
        const float* Xl = X + 2 * lane;
        for (int j = s; j < e; j += 16) {
            float2 xv[16];
            float  vv[16];
#pragma unroll
            for (int i = 0; i < 16; i++) {
                const int idx = j + i;
                int2 ev = (idx < e) ? edges[idx] : make_int2(0, 0);
                vv[i] = __int_as_float(ev.y);
                xv[i] = *(const float2*)(Xl + (size_t)ev.x * F);
            }
#pragma unroll
            for (int i = 0; i < 16; i++) {
                ax += vv[i] * xv[i].x;
                ay += vv[i] * xv[i].y;
            }
        }
        ax += bias[2 * lane];
        ay += bias[2 * lane + 1];
        ax = ax > 0.f ? ax : 0.01f * ax;
        ay = ay > 0.f ? ay : 0.01f * ay;
        float2* dst = (float2*)(out + (size_t)wid * F + 2 * lane);
        *dst = make_float2(ax, ay);
    } else {
        float a = 0.f;
        const float* Xl = X + lane;
        for (int j = s; j < e; j += 16) {
            float xv[16];
            float vv[16];
#pragma unroll
            for (int i = 0; i < 16; i++) {
                const int idx = j + i;
                int2 ev = (idx < e) ? edges[idx] : make_int2(0, 0);
                vv[i] = __int_as_float(ev.y);
                xv[i] = Xl[(size_t)ev.x * F];
            }
#pragma unroll
            for (int i = 0; i < 16; i++) a += vv[i] * xv[i];
        }
        a += bias[lane];
        a = a > 0.f ? a : 0.01f * a;
        out[(size_t)wid * F + lane] = a;
    }
}

// ---------------- GEMM: C = [act](A@W + [bias] [+ C]) ----------------
// BM=128, BN=64, BK=32 tiles; 8x4 micro-tile; 24KB LDS (~6 blocks/CU).
// Ash float4 slots XOR-swizzled by row-group so a wave's 4 row-groups hit
// distinct bank groups on ds_read_b128.
template<int K, bool BIAS, bool ACT, bool ACCUM>
__global__ __launch_bounds__(256) void gemm_k(
    const float* __restrict__ A,
    const float* __restrict__ W,
    const float* __restrict__ bias,
    float* __restrict__ C,
    int M, int Nfull, int ldc)
{
    constexpr int BM = 128;
    constexpr int BN = 64;
    constexpr int BK = 32;
    __shared__ float Ash[BM * BK];   // row-major, 8 f4 slots/row, slot ^ (row>>3 & 7)
    __shared__ float Wsh[BK * BN];   // [k][n]

    const int t = threadIdx.x;
    const int row0 = blockIdx.x * BM;
    const int n0 = blockIdx.y * BN;

    const int rg = t >> 4;           // row-group 0..15
    const int r0 = rg << 3;          // 8 rows per thread
    const int c0 = (t & 15) << 2;    // 4 cols per thread
    const int aswz = rg & 7;

    // staging assignments
    const int sm = t >> 1;           // A row 0..127
    const int shalf = (t & 1) << 2;  // f4 slot base 0 or 4
    const int wk = t >> 3;           // W k-row 0..31
    const int wn = (t & 7) << 3;     // W col 0..56 (2 f4 per thread)

    float acc[8][4];
#pragma unroll
    for (int i = 0; i < 8; i++)
#pragma unroll
        for (int j = 0; j < 4; j++) acc[i][j] = 0.f;

    for (int kt = 0; kt < K; kt += BK) {
        // ---- stage A tile (4 float4/thread, swizzled slots) ----
        {
            const bool ok = (row0 + sm) < M;
            const float4* src = (const float4*)(A + (size_t)(row0 + sm) * K + kt) + shalf;
            float4 v[4];
#pragma unroll
            for (int i = 0; i < 4; i++)
                v[i] = ok ? src[i] : make_float4(0.f, 0.f, 0.f, 0.f);
            const int swz = (sm >> 3) & 7;
            float4* dst = (float4*)Ash + sm * 8;
#pragma unroll
            for (int i = 0; i < 4; i++)
                dst[(shalf + i) ^ swz] = v[i];
        }
        // ---- stage W tile (2 float4/thread) ----
        {
            const float4* src = (const float4*)(W + (size_t)(kt + wk) * Nfull + n0 + wn);
            float4* dst = (float4*)Wsh + wk * 16 + (wn >> 2);
            dst[0] = src[0];
            dst[1] = src[1];
        }
        __syncthreads();

#pragma unroll
        for (int k = 0; k < BK; k += 4) {
            float4 a[8];
#pragma unroll
            for (int i = 0; i < 8; i++)
                a[i] = ((const float4*)Ash)[(r0 + i) * 8 + ((k >> 2) ^ aswz)];
            float4 w4[4];
#pragma unroll
            for (int kk = 0; kk < 4; kk++)
                w4[kk] = ((const float4*)Wsh)[(k + kk) * 16 + (c0 >> 2)];
#pragma unroll
            for (int i = 0; i < 8; i++) {
                acc[i][0] += a[i].x * w4[0].x + a[i].y * w4[1].x + a[i].z * w4[2].x + a[i].w * w4[3].x;
                acc[i][1] += a[i].x * w4[0].y + a[i].y * w4[1].y + a[i].z * w4[2].y + a[i].w * w4[3].y;
                acc[i][2] += a[i].x * w4[0].z + a[i].y * w4[1].z + a[i].z * w4[2].z + a[i].w * w4[3].z;
                acc[i][3] += a[i].x * w4[0].w + a[i].y * w4[1].w + a[i].z * w4[2].w + a[i].w * w4[3].w;
            }
        }
        __syncthreads();
    }

    float4 bv = make_float4(0.f, 0.f, 0.f, 0.f);
    if (BIAS) bv = *(const float4*)(bias + n0 + c0);
#pragma unroll
    for (int i = 0; i < 8; i++) {
        const int row = row0 + r0 + i;
        if (row < M) {
            float4 v = make_float4(acc[i][0], acc[i][1], acc[i][2], acc[i][3]);
            if (BIAS) { v.x += bv.x; v.y += bv.y; v.z += bv.z; v.w += bv.w; }
            float* cp = C + (size_t)row * ldc + n0 + c0;
            if (ACCUM) {
                float4 o = *(const float4*)cp;
                v.x += o.x; v.y += o.y; v.z += o.z; v.w += o.w;
            }
            if (ACT) {
                v.x = v.x > 0.f ? v.x : 0.01f * v.x;
                v.y = v.y > 0.f ? v.y : 0.01f * v.y;
                v.z = v.z > 0.f ? v.z : 0.01f * v.z;
                v.w = v.w > 0.f ? v.w : 0.01f * v.w;
            }
            *(float4*)cp = v;
        }
    }
}

// ---------------- semantic attention, block-tiled (LDS-staged) ----------------
template<int D, int H, int NT, int LOGH>
__global__ __launch_bounds__(256) void att2_k(
    const float* __restrict__ g0, const float* __restrict__ g1,
    const float* __restrict__ W1, const float* __restrict__ b1,
    const float* __restrict__ W2, float* __restrict__ eo, int N)
{
    __shared__ float sg0[NT * D];
    __shared__ float sg1[NT * D];
    __shared__ float sW1[D * H];
    __shared__ float sw[2][NT];
    __shared__ float sbeta[2][NT];

    const int t = threadIdx.x;
    const int n0 = blockIdx.x * NT;
    constexpr int D4 = D / 4;

    for (int i = t; i < D * H; i += 256) sW1[i] = W1[i];
    for (int i = t; i < NT * D4; i += 256) {
        const int n = i / D4;
        float4 v0 = make_float4(0.f, 0.f, 0.f, 0.f), v1 = v0;
        if (n0 + n < N) {
            v0 = ((const float4*)(g0 + (size_t)(n0 + n) * D))[i - n * D4];
            v1 = ((const float4*)(g1 + (size_t)(n0 + n) * D))[i - n * D4];
        }
        ((float4*)sg0)[i] = v0;
        ((float4*)sg1)[i] = v1;
    }
    __syncthreads();

    constexpr int NPP = 256 / H;
    constexpr int PASSES = NT / NPP;
    const int j = t & (H - 1);
    const int nsub = t >> LOGH;
    const float b1j = b1[j];
    const float W2j = W2[j];

#pragma unroll
    for (int pass = 0; pass < PASSES; pass++) {
        const int n = pass * NPP + nsub;
#pragma unroll
        for (int p = 0; p < 2; p++) {
            const float* g = (p ? sg1 : sg0) + n * D;
            float s = b1j;
#pragma unroll 8
            for (int k = 0; k < D; k++) s += g[k] * sW1[k * H + j];
            float v = tanhf(s) * W2j;
#pragma unroll
            for (int m = 1; m < H; m <<= 1) v += __shfl_xor(v, m);
            if (j == 0) sw[p][n] = v;
        }
    }
    __syncthreads();
    if (t < NT) {
        const float w0 = sw[0][t], w1 = sw[1][t];
        const float mx = fmaxf(w0, w1);
        const float e0 = expf(w0 - mx), e1 = expf(w1 - mx);
        const float inv = 1.f / (e0 + e1);
        sbeta[0][t] = e0 * inv;
        sbeta[1][t] = e1 * inv;
    }
    __syncthreads();
    for (int i = t; i < NT * D4; i += 256) {
        const int n = i / D4;
        if (n0 + n < N) {
            const float4 a = ((const float4*)sg0)[i];
            const float4 b = ((const float4*)sg1)[i];
            const float c0 = sbeta[0][n], c1 = sbeta[1][n];
            float4 o;
            o.x = c0 * a.x + c1 * b.x;
            o.y = c0 * a.y + c1 * b.y;
            o.z = c0 * a.z + c1 * b.z;
            o.w = c0 * a.w + c1 * b.w;
            ((float4*)(eo + (size_t)(n0 + n) * D))[i - n * D4] = o;
        }
    }
}

// ---------------- launch ----------------
extern "C" void kernel_launch(void* const* d_in, const int* in_sizes, int n_in,
                              void* d_out, int out_size, void* d_ws, size_t ws_size,
                              hipStream_t stream)
{
    const float* feat = (const float*)d_in[0];
    const int*   row_aa = (const int*)d_in[1];
    const int*   col_aa = (const int*)d_in[2];
    const float* val_aa = (const float*)d_in[3];
    const int*   row_ab = (const int*)d_in[4];
    const int*   col_ab = (const int*)d_in[5];
    const float* val_ab = (const float*)d_in[6];
    const int*   row_ba = (const int*)d_in[7];
    const int*   col_ba = (const int*)d_in[8];
    const float* val_ba = (const float*)d_in[9];
    const int*   row_bb = (const int*)d_in[10];
    const int*   col_bb = (const int*)d_in[11];
    const float* val_bb = (const float*)d_in[12];
    const float* W0_aa = (const float*)d_in[13]; const float* b0_aa = (const float*)d_in[14];
    const float* W1_aa = (const float*)d_in[15]; const float* b1_aa = (const float*)d_in[16];
    const float* W0_ab = (const float*)d_in[17]; const float* b0_ab = (const float*)d_in[18];
    const float* W1_ab = (const float*)d_in[19]; const float* b1_ab = (const float*)d_in[20];
    const float* W0_ba = (const float*)d_in[21]; const float* b0_ba = (const float*)d_in[22];
    const float* W1_ba = (const float*)d_in[23]; const float* b1_ba = (const float*)d_in[24];
    const float* W0_bb = (const float*)d_in[25]; const float* b0_bb = (const float*)d_in[26];
    const float* W1_bb = (const float*)d_in[27]; const float* b1_bb = (const float*)d_in[28];
    const float* att0_a_W1 = (const float*)d_in[29];
    const float* att0_a_b1 = (const float*)d_in[30];
    const float* att0_a_W2 = (const float*)d_in[31];
    const float* att1_a_W1 = (const float*)d_in[32];
    const float* att1_a_b1 = (const float*)d_in[33];
    const float* att1_a_W2 = (const float*)d_in[34];
    const float* Wf_a = (const float*)d_in[35]; const float* bf_a = (const float*)d_in[36];
    const float* att0_b_W1 = (const float*)d_in[37];
    const float* att0_b_b1 = (const float*)d_in[38];
    const float* att0_b_W2 = (const float*)d_in[39];
    const float* att1_b_W1 = (const float*)d_in[40];
    const float* att1_b_b1 = (const float*)d_in[41];
    const float* att1_b_W2 = (const float*)d_in[42];
    const float* Wf_b = (const float*)d_in[43]; const float* bf_b = (const float*)d_in[44];

    const int E_r[4] = { in_sizes[1], in_sizes[4], in_sizes[7], in_sizes[10] };
    const int* rows_r[4] = { row_aa, row_ab, row_ba, row_bb };
    const int* cols_r[4] = { col_aa, col_ab, col_ba, col_bb };
    const float* vals_r[4] = { val_aa, val_ab, val_ba, val_bb };

    const size_t RSZ = (size_t)12800000;
    size_t Etot = (size_t)E_r[0] + E_r[1] + E_r[2] + E_r[3];
    const int bpr = (NROW + SCHUNK - 1) / SCHUNK;      // blocks per relation (25)
    size_t need = (3 * RSZ + (size_t)4 * (NROW + 1) + 8 * (size_t)NROW
                   + (size_t)4 * bpr + 2 * Etot + 32) * 4;
    if (ws_size < need) return;

    float* ws = (float*)d_ws;
    float* A0 = ws;
    float* A1 = ws + RSZ;
    float* A2 = ws + 2 * RSZ;
    float* A3 = (float*)d_out;            // e1_b lives here until final projection
    int*   rp4  = (int*)(ws + 3 * RSZ);
    int*   cnt4 = rp4 + (size_t)4 * (NROW + 1);
    int*   cur4 = cnt4 + (size_t)4 * NROW;
    int*   bsum = cur4 + (size_t)4 * NROW;
    int2*  edgesS = (int2*)(bsum + (size_t)4 * bpr);   // even word offset -> 8B aligned

    size_t eoff[4];
    eoff[0] = 0; eoff[1] = eoff[0] + E_r[0];
    eoff[2] = eoff[1] + E_r[1]; eoff[3] = eoff[2] + E_r[2];

    float* out = (float*)d_out;
    const float* fa = feat;
    const float* fb = feat + (size_t)NA * FT;

    const dim3 blk(256);
    const dim3 gG((NROW + 127) / 128, 2);     // GEMM M=100000, N=128
    const dim3 gG64((NROW + 127) / 128, 1);   // GEMM M=100000, N=64
    const int spg = (NROW * 64 + 255) / 256;   // spmm: one wave per row
    const int ag128 = (NROW + 15) / 16;        // att2 D=128, NT=16
    const int ag64  = (NROW + 31) / 32;        // att2 D=64,  NT=32

    // ================= build CSR for all 4 relations =================
    zero_k<<<(4 * NROW / 4 + 255) / 256, blk, 0, stream>>>((float4*)cnt4, 4 * NROW / 4);
    for (int r = 0; r < 4; r++)
        hist_k<<<(E_r[r] + 255) / 256, blk, 0, stream>>>(rows_r[r], cnt4 + (size_t)r * NROW, E_r[r]);
    scan1_k<<<4 * bpr, blk, 0, stream>>>(cnt4, bsum, NROW, bpr);
    scan2_k<<<1, blk, 0, stream>>>(bsum, bpr);
    scan3_k<<<4 * bpr, blk, 0, stream>>>(cnt4, bsum, rp4, cur4, NROW, bpr);
    for (int r = 0; r < 4; r++)
        scatter_k<<<(E_r[r] + 255) / 256, blk, 0, stream>>>(
            rows_r[r], cols_r[r], vals_r[r], cur4 + (size_t)r * NROW,
            edgesS + eoff[r], E_r[r]);

    const int* rp_aa = rp4;
    const int* rp_ab = rp4 + (NROW + 1);
    const int* rp_ba = rp4 + 2 * (NROW + 1);
    const int* rp_bb = rp4 + 3 * (NROW + 1);
    const int2* es_aa = edgesS + eoff[0];
    const int2* es_ab = edgesS + eoff[1];
    const int2* es_ba = edgesS + eoff[2];
    const int2* es_bb = edgesS + eoff[3];

    // ================= layer 0, type a =================
    gemm_k<128, false, false, false><<<gG, blk, 0, stream>>>(fa, W0_aa, nullptr, A0, NA, 128, 128);
    spmm_csr_k<128><<<spg, blk, 0, stream>>>(rp_aa, es_aa, A0, b0_aa, A1, NA);
    gemm_k<128, false, false, false><<<gG, blk, 0, stream>>>(fb, W0_ab, nullptr, A0, NB, 128, 128);
    spmm_csr_k<128><<<spg, blk, 0, stream>>>(rp_ab, es_ab, A0, b0_ab, A2, NA);
    att2_k<128, 32, 16, 5><<<ag128, blk, 0, stream>>>(A1, A2, att0_a_W1, att0_a_b1, att0_a_W2, A1, NA);
    // e1_a in A1

    // ================= layer 0, type b =================
    gemm_k<128, false, false, false><<<gG, blk, 0, stream>>>(fa, W0_ba, nullptr, A0, NA, 128, 128);
    spmm_csr_k<128><<<spg, blk, 0, stream>>>(rp_ba, es_ba, A0, b0_ba, A3, NB);
    gemm_k<128, false, false, false><<<gG, blk, 0, stream>>>(fb, W0_bb, nullptr, A0, NB, 128, 128);
    spmm_csr_k<128><<<spg, blk, 0, stream>>>(rp_bb, es_bb, A0, b0_bb, A2, NB);
    att2_k<128, 32, 16, 5><<<ag128, blk, 0, stream>>>(A3, A2, att0_b_W1, att0_b_b1, att0_b_W2, A3, NB);
    // e1_b in A3 (= d_out region)

    float* A0lo = A0;            float* A0hi = A0 + RSZ / 2;
    float* A2lo = A2;            float* A2hi = A2 + RSZ / 2;

    // ================= layer 1, type a =================
    gemm_k<128, false, false, false><<<gG64, blk, 0, stream>>>(A1, W1_aa, nullptr, A0lo, NA, 64, 64);
    spmm_csr_k<64><<<spg, blk, 0, stream>>>(rp_aa, es_aa, A0lo, b1_aa, A0hi, NA);
    gemm_k<128, false, false, false><<<gG64, blk, 0, stream>>>(A3, W1_ab, nullptr, A2lo, NB, 64, 64);
    spmm_csr_k<64><<<spg, blk, 0, stream>>>(rp_ab, es_ab, A2lo, b1_ab, A2hi, NA);
    att2_k<64, 16, 32, 4><<<ag64, blk, 0, stream>>>(A0hi, A2hi, att1_a_W1, att1_a_b1, att1_a_W2, A0hi, NA);
    // u_a in A0hi

    // ================= layer 1, type b =================
    gemm_k<128, false, false, false><<<gG64, blk, 0, stream>>>(A1, W1_ba, nullptr, A2lo, NA, 64, 64);
    spmm_csr_k<64><<<spg, blk, 0, stream>>>(rp_ba, es_ba, A2lo, b1_ba, A2hi, NB);
    gemm_k<128, false, false, false><<<gG64, blk, 0, stream>>>(A3, W1_bb, nullptr, A2lo, NB, 64, 64);
    spmm_csr_k<64><<<spg, blk, 0, stream>>>(rp_bb, es_bb, A2lo, b1_bb, A0lo, NB);
    att2_k<64, 16, 32, 4><<<ag64, blk, 0, stream>>>(A2hi, A0lo, att1_b_W1, att1_b_b1, att1_b_W2, A2hi, NB);
    // u_b in A2hi

    // ================= final projection =================
    gemm_k<64,  true,  false, false><<<gG64, blk, 0, stream>>>(A0hi, Wf_a, bf_a, out, NA, 64, 64);
    gemm_k<128, false, false, true ><<<gG64, blk, 0, stream>>>(fa, Wf_a + 64 * 64, nullptr, out, NA, 64, 64);
    gemm_k<64,  true,  false, false><<<gG64, blk, 0, stream>>>(A2hi, Wf_b, bf_b, out + (size_t)NA * OUTD, NB, 64, 64);
    gemm_k<128, false, false, true ><<<gG64, blk, 0, stream>>>(fb, Wf_b + 64 * 64, nullptr, out + (size_t)NA * OUTD, NB, 64, 64);
}

// Round 2
// 2683.452 us; speedup vs baseline: 1.1659x; 1.1659x over previous
//
#include <hip/hip_runtime.h>
#include <hip/hip_fp16.h>
#include <math.h>

#define NA 100000
#define NB 100000
#define NROW 100000   // all four relations have 100000 output rows
#define FT 128
#define H1 128
#define H2 64
#define OUTD 64
#define SCHUNK 4096   // elements per scan block

// ---------------- zero fill (used for CSR count arrays) ----------------
__global__ __launch_bounds__(256) void zero_k(float4* __restrict__ p, int n4) {
    int i = blockIdx.x * 256 + threadIdx.x;
    if (i < n4) p[i] = make_float4(0.f, 0.f, 0.f, 0.f);
}

// ---------------- CSR build: histogram ----------------
__global__ __launch_bounds__(256) void hist_k(const int* __restrict__ rows,
                                              int* __restrict__ cnt, int E) {
    int i = blockIdx.x * 256 + threadIdx.x;
    if (i < E) atomicAdd(&cnt[rows[i]], 1);
}

// ---------------- multi-block segmented exclusive scan ----------------
// phase 1: per-block sums (grid = 4 * bpr)
__global__ __launch_bounds__(256) void scan1_k(const int* __restrict__ cnt4,
                                               int* __restrict__ bsum, int N, int bpr) {
    const int r = blockIdx.x / bpr;
    const int b = blockIdx.x - r * bpr;
    const int* cnt = cnt4 + (size_t)r * N + (size_t)b * SCHUNK;
    const int count = min(SCHUNK, N - b * SCHUNK);
    const int t = threadIdx.x;
    int s = 0;
    for (int i = t; i < count; i += 256) s += cnt[i];
#pragma unroll
    for (int m = 1; m < 64; m <<= 1) s += __shfl_xor(s, m);
    __shared__ int sh[4];
    if ((t & 63) == 0) sh[t >> 6] = s;
    __syncthreads();
    if (t == 0) bsum[blockIdx.x] = sh[0] + sh[1] + sh[2] + sh[3];
}

// phase 2: exclusive scan of block sums, one wave per relation (bpr <= 64)
__global__ __launch_bounds__(256) void scan2_k(int* __restrict__ bsum, int bpr) {
    const int lane = threadIdx.x & 63;
    const int r = threadIdx.x >> 6;
    int v = (lane < bpr) ? bsum[r * bpr + lane] : 0;
    int inc = v;
#pragma unroll
    for (int m = 1; m < 64; m <<= 1) {
        int u = __shfl_up(inc, m);
        if (lane >= m) inc += u;
    }
    if (lane < bpr) bsum[r * bpr + lane] = inc - v;
}

// phase 3: per-block local scan + offset, write rp & cur (grid = 4 * bpr)
__global__ __launch_bounds__(256) void scan3_k(const int* __restrict__ cnt4,
                                               const int* __restrict__ bsum,
                                               int* __restrict__ rp4,
                                               int* __restrict__ cur4, int N, int bpr) {
    const int r = blockIdx.x / bpr;
    const int b = blockIdx.x - r * bpr;
    const int base0 = b * SCHUNK;
    const int* cnt = cnt4 + (size_t)r * N;
    int* rp  = rp4  + (size_t)r * (N + 1);
    int* cur = cur4 + (size_t)r * N;
    const int count = min(SCHUNK, N - base0);
    const int t = threadIdx.x;
    const int off = base0 + t * 16;

    int v[16];
    int tot = 0;
#pragma unroll
    for (int i = 0; i < 16; i++) {
        const int idx = off + i;
        v[i] = (idx < base0 + count) ? cnt[idx] : 0;
        tot += v[i];
    }
    // wave inclusive scan of per-thread totals
    int inc = tot;
#pragma unroll
    for (int m = 1; m < 64; m <<= 1) {
        int u = __shfl_up(inc, m);
        if ((t & 63) >= m) inc += u;
    }
    __shared__ int wsum[4];
    if ((t & 63) == 63) wsum[t >> 6] = inc;
    __syncthreads();
    int wbase = 0;
    const int w = t >> 6;
    for (int i = 0; i < 4; i++) if (i < w) wbase += wsum[i];

    int ex = inc - tot + wbase + bsum[blockIdx.x];
#pragma unroll
    for (int i = 0; i < 16; i++) {
        const int idx = off + i;
        if (idx < base0 + count) {
            rp[idx] = ex; cur[idx] = ex;
            ex += v[i];
        }
    }
    if (N - 1 >= off && N - 1 < off + 16) rp[N] = ex;
}

// ---------------- CSR build: scatter (col,val) packed int2 ----------------
__global__ __launch_bounds__(256) void scatter_k(const int* __restrict__ rows,
                                                 const int* __restrict__ cols,
                                                 const float* __restrict__ vals,
                                                 int* __restrict__ cur,
                                                 int2* __restrict__ edgesS, int E) {
    int i = blockIdx.x * 256 + threadIdx.x;
    if (i >= E) return;
    int r = rows[i];
    int pos = atomicAdd(&cur[r], 1);
    edgesS[pos] = make_int2(cols[i], __float_as_int(vals[i]));
}

// ---------------- SpMM (CSR gather), fused bias + LeakyReLU ----------------
// One wave per output row; X is fp16 (halves gather bytes: 256B/edge at F=128,
// 128B/edge at F=64, still fully coalesced). 4 gathers in flight, no dummies.
template<int F>
__global__ __launch_bounds__(256) void spmm_csr_k(
    const int* __restrict__ rp, const int2* __restrict__ edges,
    const __half* __restrict__ X,
    const float* __restrict__ bias, float* __restrict__ out, int N)
{
    const int wid  = (blockIdx.x * 256 + threadIdx.x) >> 6;
    const int lane = threadIdx.x & 63;
    if (wid >= N) return;
    const int s = rp[wid];
    const int e = rp[wid + 1];

    if (F == 128) {
        float ax = 0.f, ay = 0.f;
        const __half2* Xl = (const __half2*)X + lane;   // row c -> Xl[c * 64]
        int j = s;
        for (; j + 3 < e; j += 4) {
            int2 e0 = edges[j], e1 = edges[j+1], e2 = edges[j+2], e3 = edges[j+3];
            __half2 h0 = Xl[(size_t)e0.x * 64];
            __half2 h1 = Xl[(size_t)e1.x * 64];
            __half2 h2 = Xl[(size_t)e2.x * 64];
            __half2 h3 = Xl[(size_t)e3.x * 64];
            float2 x0 = __half22float2(h0);
            float2 x1 = __half22float2(h1);
            float2 x2 = __half22float2(h2);
            float2 x3 = __half22float2(h3);
            const float v0 = __int_as_float(e0.y), v1 = __int_as_float(e1.y);
            const float v2 = __int_as_float(e2.y), v3 = __int_as_float(e3.y);
            ax += v0 * x0.x + v1 * x1.x + v2 * x2.x + v3 * x3.x;
            ay += v0 * x0.y + v1 * x1.y + v2 * x2.y + v3 * x3.y;
        }
        for (; j < e; j++) {
            int2 ev = edges[j];
            float2 x = __half22float2(Xl[(size_t)ev.x * 64]);
            const float v = __int_as_float(ev.y);
            ax += v * x.x; ay += v * x.y;
        }
        ax += bias[2 * lane];
        ay += bias[2 * lane + 1];
        ax = ax > 0.f ? ax : 0.01f * ax;
        ay = ay > 0.f ? ay : 0.01f * ay;
        float2* dst = (float2*)(out + (size_t)wid * F + 2 * lane);
        *dst = make_float2(ax, ay);
    } else {
        float a = 0.f;
        const __half* Xl = X + lane;                    // row c -> Xl[c * 64]
        int j = s;
        for (; j + 3 < e; j += 4) {
            int2 e0 = edges[j], e1 = edges[j+1], e2 = edges[j+2], e3 = edges[j+3];
            float x0 = __half2float(Xl[(size_t)e0.x * 64]);
            float x1 = __half2float(Xl[(size_t)e1.x * 64]);
            float x2 = __half2float(Xl[(size_t)e2.x * 64]);
            float x3 = __half2float(Xl[(size_t)e3.x * 64]);
            a += __int_as_float(e0.y) * x0 + __int_as_float(e1.y) * x1
               + __int_as_float(e2.y) * x2 + __int_as_float(e3.y) * x3;
        }
        for (; j < e; j++) {
            int2 ev = edges[j];
            a += __int_as_float(ev.y) * __half2float(Xl[(size_t)ev.x * 64]);
        }
        a += bias[lane];
        a = a > 0.f ? a : 0.01f * a;
        out[(size_t)wid * F + lane] = a;
    }
}

// ---------------- GEMM: C = [act](A@W + [bias] [+ C]) ----------------
// BM=128, BN=64, BK=32 tiles; 8x4 micro-tile; 24KB LDS. HOUT stores C as fp16
// (used for the pre-aggregation X@W buffers the spmm gathers from).
template<int K, bool BIAS, bool ACT, bool ACCUM, bool HOUT>
__global__ __launch_bounds__(256) void gemm_k(
    const float* __restrict__ A,
    const float* __restrict__ W,
    const float* __restrict__ bias,
    float* __restrict__ C,
    int M, int Nfull, int ldc)
{
    constexpr int BM = 128;
    constexpr int BN = 64;
    constexpr int BK = 32;
    __shared__ float Ash[BM * BK];   // row-major, 8 f4 slots/row, slot ^ (row>>3 & 7)
    __shared__ float Wsh[BK * BN];   // [k][n]

    const int t = threadIdx.x;
    const int row0 = blockIdx.x * BM;
    const int n0 = blockIdx.y * BN;

    const int rg = t >> 4;           // row-group 0..15
    const int r0 = rg << 3;          // 8 rows per thread
    const int c0 = (t & 15) << 2;    // 4 cols per thread
    const int aswz = rg & 7;

    // staging assignments
    const int sm = t >> 1;           // A row 0..127
    const int shalf = (t & 1) << 2;  // f4 slot base 0 or 4
    const int wk = t >> 3;           // W k-row 0..31
    const int wn = (t & 7) << 3;     // W col (2 f4 per thread)

    float acc[8][4];
#pragma unroll
    for (int i = 0; i < 8; i++)
#pragma unroll
        for (int j = 0; j < 4; j++) acc[i][j] = 0.f;

    for (int kt = 0; kt < K; kt += BK) {
        // ---- stage A tile (4 float4/thread, swizzled slots) ----
        {
            const bool ok = (row0 + sm) < M;
            const float4* src = (const float4*)(A + (size_t)(row0 + sm) * K + kt) + shalf;
            float4 v[4];
#pragma unroll
            for (int i = 0; i < 4; i++)
                v[i] = ok ? src[i] : make_float4(0.f, 0.f, 0.f, 0.f);
            const int swz = (sm >> 3) & 7;
            float4* dst = (float4*)Ash + sm * 8;
#pragma unroll
            for (int i = 0; i < 4; i++)
                dst[(shalf + i) ^ swz] = v[i];
        }
        // ---- stage W tile (2 float4/thread) ----
        {
            const float4* src = (const float4*)(W + (size_t)(kt + wk) * Nfull + n0 + wn);
            float4* dst = (float4*)Wsh + wk * 16 + (wn >> 2);
            dst[0] = src[0];
            dst[1] = src[1];
        }
        __syncthreads();

#pragma unroll
        for (int k = 0; k < BK; k += 4) {
            float4 a[8];
#pragma unroll
            for (int i = 0; i < 8; i++)
                a[i] = ((const float4*)Ash)[(r0 + i) * 8 + ((k >> 2) ^ aswz)];
            float4 w4[4];
#pragma unroll
            for (int kk = 0; kk < 4; kk++)
                w4[kk] = ((const float4*)Wsh)[(k + kk) * 16 + (c0 >> 2)];
#pragma unroll
            for (int i = 0; i < 8; i++) {
                acc[i][0] += a[i].x * w4[0].x + a[i].y * w4[1].x + a[i].z * w4[2].x + a[i].w * w4[3].x;
                acc[i][1] += a[i].x * w4[0].y + a[i].y * w4[1].y + a[i].z * w4[2].y + a[i].w * w4[3].y;
                acc[i][2] += a[i].x * w4[0].z + a[i].y * w4[1].z + a[i].z * w4[2].z + a[i].w * w4[3].z;
                acc[i][3] += a[i].x * w4[0].w + a[i].y * w4[1].w + a[i].z * w4[2].w + a[i].w * w4[3].w;
            }
        }
        __syncthreads();
    }

    float4 bv = make_float4(0.f, 0.f, 0.f, 0.f);
    if (BIAS) bv = *(const float4*)(bias + n0 + c0);
#pragma unroll
    for (int i = 0; i < 8; i++) {
        const int row = row0 + r0 + i;
        if (row < M) {
            float4 v = make_float4(acc[i][0], acc[i][1], acc[i][2], acc[i][3]);
            if (BIAS) { v.x += bv.x; v.y += bv.y; v.z += bv.z; v.w += bv.w; }
            if (HOUT) {
                __half2* cp = (__half2*)((__half*)C + (size_t)row * ldc + n0 + c0);
                cp[0] = __floats2half2_rn(v.x, v.y);
                cp[1] = __floats2half2_rn(v.z, v.w);
            } else {
                float* cp = C + (size_t)row * ldc + n0 + c0;
                if (ACCUM) {
                    float4 o = *(const float4*)cp;
                    v.x += o.x; v.y += o.y; v.z += o.z; v.w += o.w;
                }
                if (ACT) {
                    v.x = v.x > 0.f ? v.x : 0.01f * v.x;
                    v.y = v.y > 0.f ? v.y : 0.01f * v.y;
                    v.z = v.z > 0.f ? v.z : 0.01f * v.z;
                    v.w = v.w > 0.f ? v.w : 0.01f * v.w;
                }
                *(float4*)cp = v;
            }
        }
    }
}

// ---------------- semantic attention, block-tiled (LDS-staged) ----------------
template<int D, int H, int NT, int LOGH>
__global__ __launch_bounds__(256) void att2_k(
    const float* __restrict__ g0, const float* __restrict__ g1,
    const float* __restrict__ W1, const float* __restrict__ b1,
    const float* __restrict__ W2, float* __restrict__ eo, int N)
{
    __shared__ float sg0[NT * D];
    __shared__ float sg1[NT * D];
    __shared__ float sW1[D * H];
    __shared__ float sw[2][NT];
    __shared__ float sbeta[2][NT];

    const int t = threadIdx.x;
    const int n0 = blockIdx.x * NT;
    constexpr int D4 = D / 4;

    for (int i = t; i < D * H; i += 256) sW1[i] = W1[i];
    for (int i = t; i < NT * D4; i += 256) {
        const int n = i / D4;
        float4 v0 = make_float4(0.f, 0.f, 0.f, 0.f), v1 = v0;
        if (n0 + n < N) {
            v0 = ((const float4*)(g0 + (size_t)(n0 + n) * D))[i - n * D4];
            v1 = ((const float4*)(g1 + (size_t)(n0 + n) * D))[i - n * D4];
        }
        ((float4*)sg0)[i] = v0;
        ((float4*)sg1)[i] = v1;
    }
    __syncthreads();

    constexpr int NPP = 256 / H;
    constexpr int PASSES = NT / NPP;
    const int j = t & (H - 1);
    const int nsub = t >> LOGH;
    const float b1j = b1[j];
    const float W2j = W2[j];

#pragma unroll
    for (int pass = 0; pass < PASSES; pass++) {
        const int n = pass * NPP + nsub;
#pragma unroll
        for (int p = 0; p < 2; p++) {
            const float* g = (p ? sg1 : sg0) + n * D;
            float s = b1j;
#pragma unroll 8
            for (int k = 0; k < D; k++) s += g[k] * sW1[k * H + j];
            float v = tanhf(s) * W2j;
#pragma unroll
            for (int m = 1; m < H; m <<= 1) v += __shfl_xor(v, m);
            if (j == 0) sw[p][n] = v;
        }
    }
    __syncthreads();
    if (t < NT) {
        const float w0 = sw[0][t], w1 = sw[1][t];
        const float mx = fmaxf(w0, w1);
        const float e0 = expf(w0 - mx), e1 = expf(w1 - mx);
        const float inv = 1.f / (e0 + e1);
        sbeta[0][t] = e0 * inv;
        sbeta[1][t] = e1 * inv;
    }
    __syncthreads();
    for (int i = t; i < NT * D4; i += 256) {
        const int n = i / D4;
        if (n0 + n < N) {
            const float4 a = ((const float4*)sg0)[i];
            const float4 b = ((const float4*)sg1)[i];
            const float c0 = sbeta[0][n], c1 = sbeta[1][n];
            float4 o;
            o.x = c0 * a.x + c1 * b.x;
            o.y = c0 * a.y + c1 * b.y;
            o.z = c0 * a.z + c1 * b.z;
            o.w = c0 * a.w + c1 * b.w;
            ((float4*)(eo + (size_t)(n0 + n) * D))[i - n * D4] = o;
        }
    }
}

// ---------------- launch ----------------
extern "C" void kernel_launch(void* const* d_in, const int* in_sizes, int n_in,
                              void* d_out, int out_size, void* d_ws, size_t ws_size,
                              hipStream_t stream)
{
    const float* feat = (const float*)d_in[0];
    const int*   row_aa = (const int*)d_in[1];
    const int*   col_aa = (const int*)d_in[2];
    const float* val_aa = (const float*)d_in[3];
    const int*   row_ab = (const int*)d_in[4];
    const int*   col_ab = (const int*)d_in[5];
    const float* val_ab = (const float*)d_in[6];
    const int*   row_ba = (const int*)d_in[7];
    const int*   col_ba = (const int*)d_in[8];
    const float* val_ba = (const float*)d_in[9];
    const int*   row_bb = (const int*)d_in[10];
    const int*   col_bb = (const int*)d_in[11];
    const float* val_bb = (const float*)d_in[12];
    const float* W0_aa = (const float*)d_in[13]; const float* b0_aa = (const float*)d_in[14];
    const float* W1_aa = (const float*)d_in[15]; const float* b1_aa = (const float*)d_in[16];
    const float* W0_ab = (const float*)d_in[17]; const float* b0_ab = (const float*)d_in[18];
    const float* W1_ab = (const float*)d_in[19]; const float* b1_ab = (const float*)d_in[20];
    const float* W0_ba = (const float*)d_in[21]; const float* b0_ba = (const float*)d_in[22];
    const float* W1_ba = (const float*)d_in[23]; const float* b1_ba = (const float*)d_in[24];
    const float* W0_bb = (const float*)d_in[25]; const float* b0_bb = (const float*)d_in[26];
    const float* W1_bb = (const float*)d_in[27]; const float* b1_bb = (const float*)d_in[28];
    const float* att0_a_W1 = (const float*)d_in[29];
    const float* att0_a_b1 = (const float*)d_in[30];
    const float* att0_a_W2 = (const float*)d_in[31];
    const float* att1_a_W1 = (const float*)d_in[32];
    const float* att1_a_b1 = (const float*)d_in[33];
    const float* att1_a_W2 = (const float*)d_in[34];
    const float* Wf_a = (const float*)d_in[35]; const float* bf_a = (const float*)d_in[36];
    const float* att0_b_W1 = (const float*)d_in[37];
    const float* att0_b_b1 = (const float*)d_in[38];
    const float* att0_b_W2 = (const float*)d_in[39];
    const float* att1_b_W1 = (const float*)d_in[40];
    const float* att1_b_b1 = (const float*)d_in[41];
    const float* att1_b_W2 = (const float*)d_in[42];
    const float* Wf_b = (const float*)d_in[43]; const float* bf_b = (const float*)d_in[44];

    const int E_r[4] = { in_sizes[1], in_sizes[4], in_sizes[7], in_sizes[10] };
    const int* rows_r[4] = { row_aa, row_ab, row_ba, row_bb };
    const int* cols_r[4] = { col_aa, col_ab, col_ba, col_bb };
    const float* vals_r[4] = { val_aa, val_ab, val_ba, val_bb };

    const size_t RSZ = (size_t)12800000;
    size_t Etot = (size_t)E_r[0] + E_r[1] + E_r[2] + E_r[3];
    const int bpr = (NROW + SCHUNK - 1) / SCHUNK;      // blocks per relation (25)
    size_t need = (3 * RSZ + (size_t)4 * (NROW + 1) + 8 * (size_t)NROW
                   + (size_t)4 * bpr + 2 * Etot + 32) * 4;
    if (ws_size < need) return;

    float* ws = (float*)d_ws;
    float* A0 = ws;
    float* A1 = ws + RSZ;
    float* A2 = ws + 2 * RSZ;
    float* A3 = (float*)d_out;            // e1_b lives here until final projection
    int*   rp4  = (int*)(ws + 3 * RSZ);
    int*   cnt4 = rp4 + (size_t)4 * (NROW + 1);
    int*   cur4 = cnt4 + (size_t)4 * NROW;
    int*   bsum = cur4 + (size_t)4 * NROW;
    int2*  edgesS = (int2*)(bsum + (size_t)4 * bpr);   // even word offset -> 8B aligned

    size_t eoff[4];
    eoff[0] = 0; eoff[1] = eoff[0] + E_r[0];
    eoff[2] = eoff[1] + E_r[1]; eoff[3] = eoff[2] + E_r[2];

    float* out = (float*)d_out;
    const float* fa = feat;
    const float* fb = feat + (size_t)NA * FT;

    const dim3 blk(256);
    const dim3 gG((NROW + 127) / 128, 2);     // GEMM M=100000, N=128
    const dim3 gG64((NROW + 127) / 128, 1);   // GEMM M=100000, N=64
    const int spg = (NROW * 64 + 255) / 256;   // spmm: one wave per row
    const int ag128 = (NROW + 15) / 16;        // att2 D=128, NT=16
    const int ag64  = (NROW + 31) / 32;        // att2 D=64,  NT=32

    // ================= build CSR for all 4 relations =================
    zero_k<<<(4 * NROW / 4 + 255) / 256, blk, 0, stream>>>((float4*)cnt4, 4 * NROW / 4);
    for (int r = 0; r < 4; r++)
        hist_k<<<(E_r[r] + 255) / 256, blk, 0, stream>>>(rows_r[r], cnt4 + (size_t)r * NROW, E_r[r]);
    scan1_k<<<4 * bpr, blk, 0, stream>>>(cnt4, bsum, NROW, bpr);
    scan2_k<<<1, blk, 0, stream>>>(bsum, bpr);
    scan3_k<<<4 * bpr, blk, 0, stream>>>(cnt4, bsum, rp4, cur4, NROW, bpr);
    for (int r = 0; r < 4; r++)
        scatter_k<<<(E_r[r] + 255) / 256, blk, 0, stream>>>(
            rows_r[r], cols_r[r], vals_r[r], cur4 + (size_t)r * NROW,
            edgesS + eoff[r], E_r[r]);

    const int* rp_aa = rp4;
    const int* rp_ab = rp4 + (NROW + 1);
    const int* rp_ba = rp4 + 2 * (NROW + 1);
    const int* rp_bb = rp4 + 3 * (NROW + 1);
    const int2* es_aa = edgesS + eoff[0];
    const int2* es_ab = edgesS + eoff[1];
    const int2* es_ba = edgesS + eoff[2];
    const int2* es_bb = edgesS + eoff[3];

    const __half* H0 = (const __half*)A0;   // fp16 view of the pre-agg buffer

    // ================= layer 0, type a =================
    gemm_k<128, false, false, false, true ><<<gG, blk, 0, stream>>>(fa, W0_aa, nullptr, A0, NA, 128, 128);
    spmm_csr_k<128><<<spg, blk, 0, stream>>>(rp_aa, es_aa, H0, b0_aa, A1, NA);
    gemm_k<128, false, false, false, true ><<<gG, blk, 0, stream>>>(fb, W0_ab, nullptr, A0, NB, 128, 128);
    spmm_csr_k<128><<<spg, blk, 0, stream>>>(rp_ab, es_ab, H0, b0_ab, A2, NA);
    att2_k<128, 32, 16, 5><<<ag128, blk, 0, stream>>>(A1, A2, att0_a_W1, att0_a_b1, att0_a_W2, A1, NA);
    // e1_a in A1

    // ================= layer 0, type b =================
    gemm_k<128, false, false, false, true ><<<gG, blk, 0, stream>>>(fa, W0_ba, nullptr, A0, NA, 128, 128);
    spmm_csr_k<128><<<spg, blk, 0, stream>>>(rp_ba, es_ba, H0, b0_ba, A3, NB);
    gemm_k<128, false, false, false, true ><<<gG, blk, 0, stream>>>(fb, W0_bb, nullptr, A0, NB, 128, 128);
    spmm_csr_k<128><<<spg, blk, 0, stream>>>(rp_bb, es_bb, H0, b0_bb, A2, NB);
    att2_k<128, 32, 16, 5><<<ag128, blk, 0, stream>>>(A3, A2, att0_b_W1, att0_b_b1, att0_b_W2, A3, NB);
    // e1_b in A3 (= d_out region)

    float* A0lo = A0;            float* A0hi = A0 + RSZ / 2;
    float* A2lo = A2;            float* A2hi = A2 + RSZ / 2;
    const __half* H0lo = (const __half*)A0lo;
    const __half* H2lo = (const __half*)A2lo;

    // ================= layer 1, type a =================
    gemm_k<128, false, false, false, true ><<<gG64, blk, 0, stream>>>(A1, W1_aa, nullptr, A0lo, NA, 64, 64);
    spmm_csr_k<64><<<spg, blk, 0, stream>>>(rp_aa, es_aa, H0lo, b1_aa, A0hi, NA);
    gemm_k<128, false, false, false, true ><<<gG64, blk, 0, stream>>>(A3, W1_ab, nullptr, A2lo, NB, 64, 64);
    spmm_csr_k<64><<<spg, blk, 0, stream>>>(rp_ab, es_ab, H2lo, b1_ab, A2hi, NA);
    att2_k<64, 16, 32, 4><<<ag64, blk, 0, stream>>>(A0hi, A2hi, att1_a_W1, att1_a_b1, att1_a_W2, A0hi, NA);
    // u_a in A0hi

    // ================= layer 1, type b =================
    gemm_k<128, false, false, false, true ><<<gG64, blk, 0, stream>>>(A1, W1_ba, nullptr, A2lo, NA, 64, 64);
    spmm_csr_k<64><<<spg, blk, 0, stream>>>(rp_ba, es_ba, H2lo, b1_ba, A2hi, NB);
    gemm_k<128, false, false, false, true ><<<gG64, blk, 0, stream>>>(A3, W1_bb, nullptr, A2lo, NB, 64, 64);
    spmm_csr_k<64><<<spg, blk, 0, stream>>>(rp_bb, es_bb, H2lo, b1_bb, A0lo, NB);
    att2_k<64, 16, 32, 4><<<ag64, blk, 0, stream>>>(A2hi, A0lo, att1_b_W1, att1_b_b1, att1_b_W2, A2hi, NB);
    // u_b in A2hi

    // ================= final projection =================
    gemm_k<64,  true,  false, false, false><<<gG64, blk, 0, stream>>>(A0hi, Wf_a, bf_a, out, NA, 64, 64);
    gemm_k<128, false, false, true , false><<<gG64, blk, 0, stream>>>(fa, Wf_a + 64 * 64, nullptr, out, NA, 64, 64);
    gemm_k<64,  true,  false, false, false><<<gG64, blk, 0, stream>>>(A2hi, Wf_b, bf_b, out + (size_t)NA * OUTD, NB, 64, 64);
    gemm_k<128, false, false, true , false><<<gG64, blk, 0, stream>>>(fb, Wf_b + 64 * 64, nullptr, out + (size_t)NA * OUTD, NB, 64, 64);
}

// Round 3
// 2166.968 us; speedup vs baseline: 1.4438x; 1.2383x over previous
//
#include <hip/hip_runtime.h>
#include <hip/hip_fp16.h>
#include <math.h>

#define NA 100000
#define NB 100000
#define NROW 100000   // all four relations have 100000 output rows
#define FT 128
#define H1 128
#define H2 64
#define OUTD 64

#define RBITS 8
#define NBUK  ((NROW + 255) >> 8)     // 391 buckets of 256 rows
#define BCAP  4992                    // staging capacity per bucket (mean 4096, +14 sigma)
#define CHUNK 4096                    // edges per binA block

// ---------------- zero fill (small int arrays) ----------------
__global__ __launch_bounds__(256) void zero_k(float4* __restrict__ p, int n4) {
    int i = blockIdx.x * 256 + threadIdx.x;
    if (i < n4) p[i] = make_float4(0.f, 0.f, 0.f, 0.f);
}

// ---------------- CSR build phase A: LDS bucket binning ----------------
// Block handles CHUNK edges: LDS-count 391 buckets, LDS-scan, reserve global
// runs (~391 atomics per 4096 edges), regroup in LDS, stream runs coalesced.
__global__ __launch_bounds__(256) void binA_k(
    const int* __restrict__ rows, const int* __restrict__ cols,
    const float* __restrict__ vals, int* __restrict__ gcur,
    int2* __restrict__ stag, int E)
{
    __shared__ int lcnt[NBUK];
    __shared__ int lcnt2[NBUK];
    __shared__ int loff[NBUK + 1];
    __shared__ int gb[NBUK];
    __shared__ int2 sbuf[CHUNK];
    __shared__ int wsum[4];

    const int t = threadIdx.x;
    const int base = blockIdx.x * CHUNK;
    const int n = min(CHUNK, E - base);

    for (int i = t; i < NBUK; i += 256) { lcnt[i] = 0; lcnt2[i] = 0; }
    __syncthreads();

    // pass 1: bucket counts
    for (int i = t; i < n; i += 256)
        atomicAdd(&lcnt[rows[base + i] >> RBITS], 1);
    __syncthreads();

    // exclusive scan lcnt -> loff (loff[NBUK] = n), 2 elements/thread
    {
        const int i0 = 2 * t, i1 = 2 * t + 1;
        int a = (i0 < NBUK) ? lcnt[i0] : 0;
        int b = (i1 < NBUK) ? lcnt[i1] : 0;
        int s = a + b;
        int inc = s;
#pragma unroll
        for (int m = 1; m < 64; m <<= 1) {
            int u = __shfl_up(inc, m);
            if ((t & 63) >= m) inc += u;
        }
        if ((t & 63) == 63) wsum[t >> 6] = inc;
        __syncthreads();
        int woff = 0;
        const int w = t >> 6;
        for (int i = 0; i < 4; i++) if (i < w) woff += wsum[i];
        const int ex = inc - s + woff;
        if (i0 <= NBUK) loff[i0] = ex;
        if (i1 <= NBUK) loff[i1] = ex + a;
    }
    __syncthreads();

    // reserve global runs per bucket
    for (int b = t; b < NBUK; b += 256) {
        const int c = lcnt[b];
        gb[b] = c ? atomicAdd(&gcur[b], c) : 0;
    }
    __syncthreads();

    // pass 2: place edges bucket-grouped into LDS
    for (int i = t; i < n; i += 256) {
        const int r = rows[base + i];
        const int c = cols[base + i];
        const float v = vals[base + i];
        const int b = r >> RBITS;
        const int rank = atomicAdd(&lcnt2[b], 1);
        sbuf[loff[b] + rank] = make_int2(c | ((r & 255) << 17), __float_as_int(v));
    }
    __syncthreads();

    // stream: slot -> bucket via binary search on loff
    for (int s = t; s < n; s += 256) {
        int lo = 0, hi = NBUK - 1;
        while (lo < hi) {
            const int mid = (lo + hi + 1) >> 1;
            if (loff[mid] <= s) lo = mid; else hi = mid - 1;
        }
        const int idx = gb[lo] + (s - loff[lo]);
        if (idx < BCAP) stag[(size_t)lo * BCAP + idx] = sbuf[s];
    }
}

// ---------------- CSR build: scan bucket totals (1 block per relation) ------
__global__ __launch_bounds__(256) void scanb_k(const int* __restrict__ gcur4,
                                               int* __restrict__ gbase4,
                                               int* __restrict__ rp4)
{
    __shared__ int wsum[4];
    const int rel = blockIdx.x;
    const int* gc = gcur4 + rel * NBUK;
    int* gbase = gbase4 + rel * (NBUK + 1);
    const int t = threadIdx.x;
    const int i0 = 2 * t, i1 = 2 * t + 1;
    int a = (i0 < NBUK) ? gc[i0] : 0;
    int b = (i1 < NBUK) ? gc[i1] : 0;
    int s = a + b;
    int inc = s;
#pragma unroll
    for (int m = 1; m < 64; m <<= 1) {
        int u = __shfl_up(inc, m);
        if ((t & 63) >= m) inc += u;
    }
    if ((t & 63) == 63) wsum[t >> 6] = inc;
    __syncthreads();
    int woff = 0;
    const int w = t >> 6;
    for (int i = 0; i < 4; i++) if (i < w) woff += wsum[i];
    const int ex = inc - s + woff;
    if (i0 <= NBUK) gbase[i0] = ex;
    if (i1 <= NBUK) gbase[i1] = ex + a;
    if (t == 255) rp4[(size_t)rel * (NROW + 1) + NROW] = ex + s;   // total = E_r
}

// ---------------- CSR build phase B: per-bucket place + rp ----------------
// One block per bucket: LDS row-hist (256 rows), LDS scan -> rp, place edges
// into LDS, stream final (col,val) run fully coalesced.
__global__ __launch_bounds__(256) void placeB_k(
    const int* __restrict__ gcur, const int* __restrict__ gbase,
    const int2* __restrict__ stag, int2* __restrict__ edgesS,
    int* __restrict__ rp, int Nrow)
{
    __shared__ int hist[256];
    __shared__ int hoff[256];
    __shared__ int hcur[256];
    __shared__ int2 obuf[BCAP];
    __shared__ int wsum[4];

    const int b = blockIdx.x;
    const int t = threadIdx.x;
    const int n = min(gcur[b], BCAP);
    const int2* src = stag + (size_t)b * BCAP;
    const int fbase = gbase[b];

    hist[t] = 0; hcur[t] = 0;
    __syncthreads();
    for (int s = t; s < n; s += 256)
        atomicAdd(&hist[(src[s].x >> 17) & 255], 1);
    __syncthreads();
    // exclusive scan of hist (1 element/thread)
    {
        const int a = hist[t];
        int inc = a;
#pragma unroll
        for (int m = 1; m < 64; m <<= 1) {
            int u = __shfl_up(inc, m);
            if ((t & 63) >= m) inc += u;
        }
        if ((t & 63) == 63) wsum[t >> 6] = inc;
        __syncthreads();
        int woff = 0;
        const int w = t >> 6;
        for (int i = 0; i < 4; i++) if (i < w) woff += wsum[i];
        hoff[t] = inc - a + woff;
    }
    __syncthreads();
    // rp for this bucket's rows
    const int row = (b << RBITS) + t;
    if (row < Nrow) rp[row] = fbase + hoff[t];
    // place into LDS
    for (int s = t; s < n; s += 256) {
        const int2 ev = src[s];
        const int rloc = (ev.x >> 17) & 255;
        const int rank = atomicAdd(&hcur[rloc], 1);
        obuf[hoff[rloc] + rank] = make_int2(ev.x & 0x1FFFF, ev.y);
    }
    __syncthreads();
    // stream final run, fully coalesced
    for (int s = t; s < n; s += 256)
        edgesS[fbase + s] = obuf[s];
}

// ---------------- SpMM (CSR gather), fused bias + LeakyReLU ----------------
// One wave per output row; X is fp16 (256B/edge at F=128, 128B at F=64).
template<int F>
__global__ __launch_bounds__(256) void spmm_csr_k(
    const int* __restrict__ rp, const int2* __restrict__ edges,
    const __half* __restrict__ X,
    const float* __restrict__ bias, float* __restrict__ out, int N)
{
    const int wid  = (blockIdx.x * 256 + threadIdx.x) >> 6;
    const int lane = threadIdx.x & 63;
    if (wid >= N) return;
    const int s = rp[wid];
    const int e = rp[wid + 1];

    if (F == 128) {
        float ax = 0.f, ay = 0.f;
        const __half2* Xl = (const __half2*)X + lane;   // row c -> Xl[c * 64]
        int j = s;
        for (; j + 3 < e; j += 4) {
            int2 e0 = edges[j], e1 = edges[j+1], e2 = edges[j+2], e3 = edges[j+3];
            __half2 h0 = Xl[(size_t)e0.x * 64];
            __half2 h1 = Xl[(size_t)e1.x * 64];
            __half2 h2 = Xl[(size_t)e2.x * 64];
            __half2 h3 = Xl[(size_t)e3.x * 64];
            float2 x0 = __half22float2(h0);
            float2 x1 = __half22float2(h1);
            float2 x2 = __half22float2(h2);
            float2 x3 = __half22float2(h3);
            const float v0 = __int_as_float(e0.y), v1 = __int_as_float(e1.y);
            const float v2 = __int_as_float(e2.y), v3 = __int_as_float(e3.y);
            ax += v0 * x0.x + v1 * x1.x + v2 * x2.x + v3 * x3.x;
            ay += v0 * x0.y + v1 * x1.y + v2 * x2.y + v3 * x3.y;
        }
        for (; j < e; j++) {
            int2 ev = edges[j];
            float2 x = __half22float2(Xl[(size_t)ev.x * 64]);
            const float v = __int_as_float(ev.y);
            ax += v * x.x; ay += v * x.y;
        }
        ax += bias[2 * lane];
        ay += bias[2 * lane + 1];
        ax = ax > 0.f ? ax : 0.01f * ax;
        ay = ay > 0.f ? ay : 0.01f * ay;
        float2* dst = (float2*)(out + (size_t)wid * F + 2 * lane);
        *dst = make_float2(ax, ay);
    } else {
        float a = 0.f;
        const __half* Xl = X + lane;                    // row c -> Xl[c * 64]
        int j = s;
        for (; j + 3 < e; j += 4) {
            int2 e0 = edges[j], e1 = edges[j+1], e2 = edges[j+2], e3 = edges[j+3];
            float x0 = __half2float(Xl[(size_t)e0.x * 64]);
            float x1 = __half2float(Xl[(size_t)e1.x * 64]);
            float x2 = __half2float(Xl[(size_t)e2.x * 64]);
            float x3 = __half2float(Xl[(size_t)e3.x * 64]);
            a += __int_as_float(e0.y) * x0 + __int_as_float(e1.y) * x1
               + __int_as_float(e2.y) * x2 + __int_as_float(e3.y) * x3;
        }
        for (; j < e; j++) {
            int2 ev = edges[j];
            a += __int_as_float(ev.y) * __half2float(Xl[(size_t)ev.x * 64]);
        }
        a += bias[lane];
        a = a > 0.f ? a : 0.01f * a;
        out[(size_t)wid * F + lane] = a;
    }
}

// ---------------- GEMM: C = [act](A@W + [bias] [+ C]) ----------------
// BM=128, BN=64, BK=32 tiles; 8x4 micro-tile; 24KB LDS. HOUT stores C as fp16.
template<int K, bool BIAS, bool ACT, bool ACCUM, bool HOUT>
__global__ __launch_bounds__(256) void gemm_k(
    const float* __restrict__ A,
    const float* __restrict__ W,
    const float* __restrict__ bias,
    float* __restrict__ C,
    int M, int Nfull, int ldc)
{
    constexpr int BM = 128;
    constexpr int BN = 64;
    constexpr int BK = 32;
    __shared__ float Ash[BM * BK];   // row-major, 8 f4 slots/row, slot ^ (row>>3 & 7)
    __shared__ float Wsh[BK * BN];   // [k][n]

    const int t = threadIdx.x;
    const int row0 = blockIdx.x * BM;
    const int n0 = blockIdx.y * BN;

    const int rg = t >> 4;           // row-group 0..15
    const int r0 = rg << 3;          // 8 rows per thread
    const int c0 = (t & 15) << 2;    // 4 cols per thread
    const int aswz = rg & 7;

    // staging assignments
    const int sm = t >> 1;           // A row 0..127
    const int shalf = (t & 1) << 2;  // f4 slot base 0 or 4
    const int wk = t >> 3;           // W k-row 0..31
    const int wn = (t & 7) << 3;     // W col (2 f4 per thread)

    float acc[8][4];
#pragma unroll
    for (int i = 0; i < 8; i++)
#pragma unroll
        for (int j = 0; j < 4; j++) acc[i][j] = 0.f;

    for (int kt = 0; kt < K; kt += BK) {
        // ---- stage A tile (4 float4/thread, swizzled slots) ----
        {
            const bool ok = (row0 + sm) < M;
            const float4* src = (const float4*)(A + (size_t)(row0 + sm) * K + kt) + shalf;
            float4 v[4];
#pragma unroll
            for (int i = 0; i < 4; i++)
                v[i] = ok ? src[i] : make_float4(0.f, 0.f, 0.f, 0.f);
            const int swz = (sm >> 3) & 7;
            float4* dst = (float4*)Ash + sm * 8;
#pragma unroll
            for (int i = 0; i < 4; i++)
                dst[(shalf + i) ^ swz] = v[i];
        }
        // ---- stage W tile (2 float4/thread) ----
        {
            const float4* src = (const float4*)(W + (size_t)(kt + wk) * Nfull + n0 + wn);
            float4* dst = (float4*)Wsh + wk * 16 + (wn >> 2);
            dst[0] = src[0];
            dst[1] = src[1];
        }
        __syncthreads();

#pragma unroll
        for (int k = 0; k < BK; k += 4) {
            float4 a[8];
#pragma unroll
            for (int i = 0; i < 8; i++)
                a[i] = ((const float4*)Ash)[(r0 + i) * 8 + ((k >> 2) ^ aswz)];
            float4 w4[4];
#pragma unroll
            for (int kk = 0; kk < 4; kk++)
                w4[kk] = ((const float4*)Wsh)[(k + kk) * 16 + (c0 >> 2)];
#pragma unroll
            for (int i = 0; i < 8; i++) {
                acc[i][0] += a[i].x * w4[0].x + a[i].y * w4[1].x + a[i].z * w4[2].x + a[i].w * w4[3].x;
                acc[i][1] += a[i].x * w4[0].y + a[i].y * w4[1].y + a[i].z * w4[2].y + a[i].w * w4[3].y;
                acc[i][2] += a[i].x * w4[0].z + a[i].y * w4[1].z + a[i].z * w4[2].z + a[i].w * w4[3].z;
                acc[i][3] += a[i].x * w4[0].w + a[i].y * w4[1].w + a[i].z * w4[2].w + a[i].w * w4[3].w;
            }
        }
        __syncthreads();
    }

    float4 bv = make_float4(0.f, 0.f, 0.f, 0.f);
    if (BIAS) bv = *(const float4*)(bias + n0 + c0);
#pragma unroll
    for (int i = 0; i < 8; i++) {
        const int row = row0 + r0 + i;
        if (row < M) {
            float4 v = make_float4(acc[i][0], acc[i][1], acc[i][2], acc[i][3]);
            if (BIAS) { v.x += bv.x; v.y += bv.y; v.z += bv.z; v.w += bv.w; }
            if (HOUT) {
                __half2* cp = (__half2*)((__half*)C + (size_t)row * ldc + n0 + c0);
                cp[0] = __floats2half2_rn(v.x, v.y);
                cp[1] = __floats2half2_rn(v.z, v.w);
            } else {
                float* cp = C + (size_t)row * ldc + n0 + c0;
                if (ACCUM) {
                    float4 o = *(const float4*)cp;
                    v.x += o.x; v.y += o.y; v.z += o.z; v.w += o.w;
                }
                if (ACT) {
                    v.x = v.x > 0.f ? v.x : 0.01f * v.x;
                    v.y = v.y > 0.f ? v.y : 0.01f * v.y;
                    v.z = v.z > 0.f ? v.z : 0.01f * v.z;
                    v.w = v.w > 0.f ? v.w : 0.01f * v.w;
                }
                *(float4*)cp = v;
            }
        }
    }
}

// ---------------- semantic attention, block-tiled (LDS-staged) ----------------
template<int D, int H, int NT, int LOGH>
__global__ __launch_bounds__(256) void att2_k(
    const float* __restrict__ g0, const float* __restrict__ g1,
    const float* __restrict__ W1, const float* __restrict__ b1,
    const float* __restrict__ W2, float* __restrict__ eo, int N)
{
    __shared__ float sg0[NT * D];
    __shared__ float sg1[NT * D];
    __shared__ float sW1[D * H];
    __shared__ float sw[2][NT];
    __shared__ float sbeta[2][NT];

    const int t = threadIdx.x;
    const int n0 = blockIdx.x * NT;
    constexpr int D4 = D / 4;

    for (int i = t; i < D * H; i += 256) sW1[i] = W1[i];
    for (int i = t; i < NT * D4; i += 256) {
        const int n = i / D4;
        float4 v0 = make_float4(0.f, 0.f, 0.f, 0.f), v1 = v0;
        if (n0 + n < N) {
            v0 = ((const float4*)(g0 + (size_t)(n0 + n) * D))[i - n * D4];
            v1 = ((const float4*)(g1 + (size_t)(n0 + n) * D))[i - n * D4];
        }
        ((float4*)sg0)[i] = v0;
        ((float4*)sg1)[i] = v1;
    }
    __syncthreads();

    constexpr int NPP = 256 / H;
    constexpr int PASSES = NT / NPP;
    const int j = t & (H - 1);
    const int nsub = t >> LOGH;
    const float b1j = b1[j];
    const float W2j = W2[j];

#pragma unroll
    for (int pass = 0; pass < PASSES; pass++) {
        const int n = pass * NPP + nsub;
#pragma unroll
        for (int p = 0; p < 2; p++) {
            const float* g = (p ? sg1 : sg0) + n * D;
            float s = b1j;
#pragma unroll 8
            for (int k = 0; k < D; k++) s += g[k] * sW1[k * H + j];
            float v = tanhf(s) * W2j;
#pragma unroll
            for (int m = 1; m < H; m <<= 1) v += __shfl_xor(v, m);
            if (j == 0) sw[p][n] = v;
        }
    }
    __syncthreads();
    if (t < NT) {
        const float w0 = sw[0][t], w1 = sw[1][t];
        const float mx = fmaxf(w0, w1);
        const float e0 = expf(w0 - mx), e1 = expf(w1 - mx);
        const float inv = 1.f / (e0 + e1);
        sbeta[0][t] = e0 * inv;
        sbeta[1][t] = e1 * inv;
    }
    __syncthreads();
    for (int i = t; i < NT * D4; i += 256) {
        const int n = i / D4;
        if (n0 + n < N) {
            const float4 a = ((const float4*)sg0)[i];
            const float4 b = ((const float4*)sg1)[i];
            const float c0 = sbeta[0][n], c1 = sbeta[1][n];
            float4 o;
            o.x = c0 * a.x + c1 * b.x;
            o.y = c0 * a.y + c1 * b.y;
            o.z = c0 * a.z + c1 * b.z;
            o.w = c0 * a.w + c1 * b.w;
            ((float4*)(eo + (size_t)(n0 + n) * D))[i - n * D4] = o;
        }
    }
}

// ---------------- launch ----------------
extern "C" void kernel_launch(void* const* d_in, const int* in_sizes, int n_in,
                              void* d_out, int out_size, void* d_ws, size_t ws_size,
                              hipStream_t stream)
{
    const float* feat = (const float*)d_in[0];
    const int*   row_aa = (const int*)d_in[1];
    const int*   col_aa = (const int*)d_in[2];
    const float* val_aa = (const float*)d_in[3];
    const int*   row_ab = (const int*)d_in[4];
    const int*   col_ab = (const int*)d_in[5];
    const float* val_ab = (const float*)d_in[6];
    const int*   row_ba = (const int*)d_in[7];
    const int*   col_ba = (const int*)d_in[8];
    const float* val_ba = (const float*)d_in[9];
    const int*   row_bb = (const int*)d_in[10];
    const int*   col_bb = (const int*)d_in[11];
    const float* val_bb = (const float*)d_in[12];
    const float* W0_aa = (const float*)d_in[13]; const float* b0_aa = (const float*)d_in[14];
    const float* W1_aa = (const float*)d_in[15]; const float* b1_aa = (const float*)d_in[16];
    const float* W0_ab = (const float*)d_in[17]; const float* b0_ab = (const float*)d_in[18];
    const float* W1_ab = (const float*)d_in[19]; const float* b1_ab = (const float*)d_in[20];
    const float* W0_ba = (const float*)d_in[21]; const float* b0_ba = (const float*)d_in[22];
    const float* W1_ba = (const float*)d_in[23]; const float* b1_ba = (const float*)d_in[24];
    const float* W0_bb = (const float*)d_in[25]; const float* b0_bb = (const float*)d_in[26];
    const float* W1_bb = (const float*)d_in[27]; const float* b1_bb = (const float*)d_in[28];
    const float* att0_a_W1 = (const float*)d_in[29];
    const float* att0_a_b1 = (const float*)d_in[30];
    const float* att0_a_W2 = (const float*)d_in[31];
    const float* att1_a_W1 = (const float*)d_in[32];
    const float* att1_a_b1 = (const float*)d_in[33];
    const float* att1_a_W2 = (const float*)d_in[34];
    const float* Wf_a = (const float*)d_in[35]; const float* bf_a = (const float*)d_in[36];
    const float* att0_b_W1 = (const float*)d_in[37];
    const float* att0_b_b1 = (const float*)d_in[38];
    const float* att0_b_W2 = (const float*)d_in[39];
    const float* att1_b_W1 = (const float*)d_in[40];
    const float* att1_b_b1 = (const float*)d_in[41];
    const float* att1_b_W2 = (const float*)d_in[42];
    const float* Wf_b = (const float*)d_in[43]; const float* bf_b = (const float*)d_in[44];

    const int E_r[4] = { in_sizes[1], in_sizes[4], in_sizes[7], in_sizes[10] };
    const int* rows_r[4] = { row_aa, row_ab, row_ba, row_bb };
    const int* cols_r[4] = { col_aa, col_ab, col_ba, col_bb };
    const float* vals_r[4] = { val_aa, val_ab, val_ba, val_bb };

    const size_t RSZ = (size_t)12800000;
    size_t Etot = (size_t)E_r[0] + E_r[1] + E_r[2] + E_r[3];
    size_t need = (3 * RSZ + (size_t)4 * (NROW + 1) + (size_t)4 * NBUK
                   + (size_t)4 * (NBUK + 1) + 2 * Etot + 64) * 4;
    if (ws_size < need) return;

    float* ws = (float*)d_ws;
    float* A0 = ws;
    float* A1 = ws + RSZ;
    float* A2 = ws + 2 * RSZ;
    float* A3 = (float*)d_out;            // e1_b lives here until final projection
    int*   rp4    = (int*)(ws + 3 * RSZ);
    int*   gcur4  = rp4 + (size_t)4 * (NROW + 1);
    int*   gbase4 = gcur4 + (size_t)4 * NBUK;
    int2*  edgesS = (int2*)(gbase4 + (size_t)4 * (NBUK + 1));
    int2*  stag   = (int2*)ws;            // staging overlaps A0/A1 (unused during build)

    size_t eoff[4];
    eoff[0] = 0; eoff[1] = eoff[0] + E_r[0];
    eoff[2] = eoff[1] + E_r[1]; eoff[3] = eoff[2] + E_r[2];

    float* out = (float*)d_out;
    const float* fa = feat;
    const float* fb = feat + (size_t)NA * FT;

    const dim3 blk(256);
    const dim3 gG((NROW + 127) / 128, 2);     // GEMM M=100000, N=128
    const dim3 gG64((NROW + 127) / 128, 1);   // GEMM M=100000, N=64
    const int spg = (NROW * 64 + 255) / 256;   // spmm: one wave per row
    const int ag128 = (NROW + 15) / 16;        // att2 D=128, NT=16
    const int ag64  = (NROW + 31) / 32;        // att2 D=64,  NT=32

    // ================= build CSR for all 4 relations =================
    zero_k<<<(4 * NBUK + 1023) / 1024, blk, 0, stream>>>((float4*)gcur4, (4 * NBUK + 3) / 4);
    for (int r = 0; r < 4; r++)
        binA_k<<<(E_r[r] + CHUNK - 1) / CHUNK, blk, 0, stream>>>(
            rows_r[r], cols_r[r], vals_r[r], gcur4 + (size_t)r * NBUK,
            stag + (size_t)r * NBUK * BCAP, E_r[r]);
    scanb_k<<<4, blk, 0, stream>>>(gcur4, gbase4, rp4);
    for (int r = 0; r < 4; r++)
        placeB_k<<<NBUK, blk, 0, stream>>>(
            gcur4 + (size_t)r * NBUK, gbase4 + (size_t)r * (NBUK + 1),
            stag + (size_t)r * NBUK * BCAP, edgesS + eoff[r],
            rp4 + (size_t)r * (NROW + 1), NROW);

    const int* rp_aa = rp4;
    const int* rp_ab = rp4 + (NROW + 1);
    const int* rp_ba = rp4 + 2 * (NROW + 1);
    const int* rp_bb = rp4 + 3 * (NROW + 1);
    const int2* es_aa = edgesS + eoff[0];
    const int2* es_ab = edgesS + eoff[1];
    const int2* es_ba = edgesS + eoff[2];
    const int2* es_bb = edgesS + eoff[3];

    const __half* H0 = (const __half*)A0;   // fp16 view of the pre-agg buffer

    // ================= layer 0, type a =================
    gemm_k<128, false, false, false, true ><<<gG, blk, 0, stream>>>(fa, W0_aa, nullptr, A0, NA, 128, 128);
    spmm_csr_k<128><<<spg, blk, 0, stream>>>(rp_aa, es_aa, H0, b0_aa, A1, NA);
    gemm_k<128, false, false, false, true ><<<gG, blk, 0, stream>>>(fb, W0_ab, nullptr, A0, NB, 128, 128);
    spmm_csr_k<128><<<spg, blk, 0, stream>>>(rp_ab, es_ab, H0, b0_ab, A2, NA);
    att2_k<128, 32, 16, 5><<<ag128, blk, 0, stream>>>(A1, A2, att0_a_W1, att0_a_b1, att0_a_W2, A1, NA);
    // e1_a in A1

    // ================= layer 0, type b =================
    gemm_k<128, false, false, false, true ><<<gG, blk, 0, stream>>>(fa, W0_ba, nullptr, A0, NA, 128, 128);
    spmm_csr_k<128><<<spg, blk, 0, stream>>>(rp_ba, es_ba, H0, b0_ba, A3, NB);
    gemm_k<128, false, false, false, true ><<<gG, blk, 0, stream>>>(fb, W0_bb, nullptr, A0, NB, 128, 128);
    spmm_csr_k<128><<<spg, blk, 0, stream>>>(rp_bb, es_bb, H0, b0_bb, A2, NB);
    att2_k<128, 32, 16, 5><<<ag128, blk, 0, stream>>>(A3, A2, att0_b_W1, att0_b_b1, att0_b_W2, A3, NB);
    // e1_b in A3 (= d_out region)

    float* A0lo = A0;            float* A0hi = A0 + RSZ / 2;
    float* A2lo = A2;            float* A2hi = A2 + RSZ / 2;
    const __half* H0lo = (const __half*)A0lo;
    const __half* H2lo = (const __half*)A2lo;

    // ================= layer 1, type a =================
    gemm_k<128, false, false, false, true ><<<gG64, blk, 0, stream>>>(A1, W1_aa, nullptr, A0lo, NA, 64, 64);
    spmm_csr_k<64><<<spg, blk, 0, stream>>>(rp_aa, es_aa, H0lo, b1_aa, A0hi, NA);
    gemm_k<128, false, false, false, true ><<<gG64, blk, 0, stream>>>(A3, W1_ab, nullptr, A2lo, NB, 64, 64);
    spmm_csr_k<64><<<spg, blk, 0, stream>>>(rp_ab, es_ab, H2lo, b1_ab, A2hi, NA);
    att2_k<64, 16, 32, 4><<<ag64, blk, 0, stream>>>(A0hi, A2hi, att1_a_W1, att1_a_b1, att1_a_W2, A0hi, NA);
    // u_a in A0hi

    // ================= layer 1, type b =================
    gemm_k<128, false, false, false, true ><<<gG64, blk, 0, stream>>>(A1, W1_ba, nullptr, A2lo, NA, 64, 64);
    spmm_csr_k<64><<<spg, blk, 0, stream>>>(rp_ba, es_ba, H2lo, b1_ba, A2hi, NB);
    gemm_k<128, false, false, false, true ><<<gG64, blk, 0, stream>>>(A3, W1_bb, nullptr, A2lo, NB, 64, 64);
    spmm_csr_k<64><<<spg, blk, 0, stream>>>(rp_bb, es_bb, H2lo, b1_bb, A0lo, NB);
    att2_k<64, 16, 32, 4><<<ag64, blk, 0, stream>>>(A2hi, A0lo, att1_b_W1, att1_b_b1, att1_b_W2, A2hi, NB);
    // u_b in A2hi

    // ================= final projection =================
    gemm_k<64,  true,  false, false, false><<<gG64, blk, 0, stream>>>(A0hi, Wf_a, bf_a, out, NA, 64, 64);
    gemm_k<128, false, false, true , false><<<gG64, blk, 0, stream>>>(fa, Wf_a + 64 * 64, nullptr, out, NA, 64, 64);
    gemm_k<64,  true,  false, false, false><<<gG64, blk, 0, stream>>>(A2hi, Wf_b, bf_b, out + (size_t)NA * OUTD, NB, 64, 64);
    gemm_k<128, false, false, true , false><<<gG64, blk, 0, stream>>>(fb, Wf_b + 64 * 64, nullptr, out + (size_t)NA * OUTD, NB, 64, 64);
}

// Round 4
// 1647.917 us; speedup vs baseline: 1.8986x; 1.3150x over previous
//
#include <hip/hip_runtime.h>
#include <hip/hip_fp16.h>
#include <math.h>

#define NA 100000
#define NB 100000
#define NROW 100000   // all four relations have 100000 output rows
#define FT 128
#define H1 128
#define H2 64
#define OUTD 64

#define RBITS 8
#define NBUK  ((NROW + 255) >> 8)     // 391 buckets of 256 rows
#define BCAP  4992                    // staging capacity per bucket (mean 4092, +14 sigma)
#define CHUNK 4096                    // edges per binA block

typedef __attribute__((ext_vector_type(8))) _Float16 f16x8;
typedef __attribute__((ext_vector_type(4))) float f32x4;

// ---------------- zero fill (small int arrays) ----------------
__global__ __launch_bounds__(256) void zero_k(float4* __restrict__ p, int n4) {
    int i = blockIdx.x * 256 + threadIdx.x;
    if (i < n4) p[i] = make_float4(0.f, 0.f, 0.f, 0.f);
}

// ---------------- weight convert: f32 row-major [K][N] -> fp16 col-major [N][K]
struct WJob { const float* src; int K; int N; int dstoff; };
struct WJobs { WJob j[12]; };
__global__ __launch_bounds__(256) void cvtw_k(WJobs jb, __half* __restrict__ dst) {
    const WJob w = jb.j[blockIdx.x];
    const int KN = w.K * w.N;
    __half* d = dst + w.dstoff;
    for (int i = threadIdx.x; i < KN; i += 256) {
        const int k = i / w.N, n = i - k * w.N;
        d[n * w.K + k] = (__half)w.src[i];
    }
}

// ---------------- CSR build phase A: LDS bucket binning ----------------
__global__ __launch_bounds__(256) void binA_k(
    const int* __restrict__ rows, const int* __restrict__ cols,
    const float* __restrict__ vals, int* __restrict__ gcur,
    int2* __restrict__ stag, int E)
{
    __shared__ int lcnt[NBUK];
    __shared__ int lcnt2[NBUK];
    __shared__ int loff[NBUK + 1];
    __shared__ int gb[NBUK];
    __shared__ int2 sbuf[CHUNK];
    __shared__ int wsum[4];

    const int t = threadIdx.x;
    const int base = blockIdx.x * CHUNK;
    const int n = min(CHUNK, E - base);

    for (int i = t; i < NBUK; i += 256) { lcnt[i] = 0; lcnt2[i] = 0; }
    __syncthreads();

    for (int i = t; i < n; i += 256)
        atomicAdd(&lcnt[rows[base + i] >> RBITS], 1);
    __syncthreads();

    {
        const int i0 = 2 * t, i1 = 2 * t + 1;
        int a = (i0 < NBUK) ? lcnt[i0] : 0;
        int b = (i1 < NBUK) ? lcnt[i1] : 0;
        int s = a + b;
        int inc = s;
#pragma unroll
        for (int m = 1; m < 64; m <<= 1) {
            int u = __shfl_up(inc, m);
            if ((t & 63) >= m) inc += u;
        }
        if ((t & 63) == 63) wsum[t >> 6] = inc;
        __syncthreads();
        int woff = 0;
        const int w = t >> 6;
        for (int i = 0; i < 4; i++) if (i < w) woff += wsum[i];
        const int ex = inc - s + woff;
        if (i0 <= NBUK) loff[i0] = ex;
        if (i1 <= NBUK) loff[i1] = ex + a;
    }
    __syncthreads();

    for (int b = t; b < NBUK; b += 256) {
        const int c = lcnt[b];
        gb[b] = c ? atomicAdd(&gcur[b], c) : 0;
    }
    __syncthreads();

    for (int i = t; i < n; i += 256) {
        const int r = rows[base + i];
        const int c = cols[base + i];
        const float v = vals[base + i];
        const int b = r >> RBITS;
        const int rank = atomicAdd(&lcnt2[b], 1);
        sbuf[loff[b] + rank] = make_int2(c | ((r & 255) << 17), __float_as_int(v));
    }
    __syncthreads();

    for (int s = t; s < n; s += 256) {
        int lo = 0, hi = NBUK - 1;
        while (lo < hi) {
            const int mid = (lo + hi + 1) >> 1;
            if (loff[mid] <= s) lo = mid; else hi = mid - 1;
        }
        const int idx = gb[lo] + (s - loff[lo]);
        if (idx < BCAP) stag[(size_t)lo * BCAP + idx] = sbuf[s];
    }
}

// ---------------- CSR build: scan bucket totals (1 block per relation) ------
__global__ __launch_bounds__(256) void scanb_k(const int* __restrict__ gcur4,
                                               int* __restrict__ gbase4,
                                               int* __restrict__ rp4)
{
    __shared__ int wsum[4];
    const int rel = blockIdx.x;
    const int* gc = gcur4 + rel * NBUK;
    int* gbase = gbase4 + rel * (NBUK + 1);
    const int t = threadIdx.x;
    const int i0 = 2 * t, i1 = 2 * t + 1;
    int a = (i0 < NBUK) ? gc[i0] : 0;
    int b = (i1 < NBUK) ? gc[i1] : 0;
    int s = a + b;
    int inc = s;
#pragma unroll
    for (int m = 1; m < 64; m <<= 1) {
        int u = __shfl_up(inc, m);
        if ((t & 63) >= m) inc += u;
    }
    if ((t & 63) == 63) wsum[t >> 6] = inc;
    __syncthreads();
    int woff = 0;
    const int w = t >> 6;
    for (int i = 0; i < 4; i++) if (i < w) woff += wsum[i];
    const int ex = inc - s + woff;
    if (i0 <= NBUK) gbase[i0] = ex;
    if (i1 <= NBUK) gbase[i1] = ex + a;
    if (t == 255) rp4[(size_t)rel * (NROW + 1) + NROW] = ex + s;
}

// ---------------- CSR build phase B: per-bucket place + rp ----------------
__global__ __launch_bounds__(256) void placeB_k(
    const int* __restrict__ gcur, const int* __restrict__ gbase,
    const int2* __restrict__ stag, int2* __restrict__ edgesS,
    int* __restrict__ rp, int Nrow)
{
    __shared__ int hist[256];
    __shared__ int hoff[256];
    __shared__ int hcur[256];
    __shared__ int2 obuf[BCAP];
    __shared__ int wsum[4];

    const int b = blockIdx.x;
    const int t = threadIdx.x;
    const int n = min(gcur[b], BCAP);
    const int2* src = stag + (size_t)b * BCAP;
    const int fbase = gbase[b];

    hist[t] = 0; hcur[t] = 0;
    __syncthreads();
    for (int s = t; s < n; s += 256)
        atomicAdd(&hist[(src[s].x >> 17) & 255], 1);
    __syncthreads();
    {
        const int a = hist[t];
        int inc = a;
#pragma unroll
        for (int m = 1; m < 64; m <<= 1) {
            int u = __shfl_up(inc, m);
            if ((t & 63) >= m) inc += u;
        }
        if ((t & 63) == 63) wsum[t >> 6] = inc;
        __syncthreads();
        int woff = 0;
        const int w = t >> 6;
        for (int i = 0; i < 4; i++) if (i < w) woff += wsum[i];
        hoff[t] = inc - a + woff;
    }
    __syncthreads();
    const int row = (b << RBITS) + t;
    if (row < Nrow) rp[row] = fbase + hoff[t];
    for (int s = t; s < n; s += 256) {
        const int2 ev = src[s];
        const int rloc = (ev.x >> 17) & 255;
        const int rank = atomicAdd(&hcur[rloc], 1);
        obuf[hoff[rloc] + rank] = make_int2(ev.x & 0x1FFFF, ev.y);
    }
    __syncthreads();
    for (int s = t; s < n; s += 256)
        edgesS[fbase + s] = obuf[s];
}

// ---------------- SpMM (CSR gather), fused bias + LeakyReLU ----------------
template<int F>
__global__ __launch_bounds__(256) void spmm_csr_k(
    const int* __restrict__ rp, const int2* __restrict__ edges,
    const __half* __restrict__ X,
    const float* __restrict__ bias, float* __restrict__ out, int N)
{
    const int wid  = (blockIdx.x * 256 + threadIdx.x) >> 6;
    const int lane = threadIdx.x & 63;
    if (wid >= N) return;
    const int s = rp[wid];
    const int e = rp[wid + 1];

    if (F == 128) {
        float ax = 0.f, ay = 0.f;
        const __half2* Xl = (const __half2*)X + lane;   // row c -> Xl[c * 64]
        int j = s;
        for (; j + 3 < e; j += 4) {
            int2 e0 = edges[j], e1 = edges[j+1], e2 = edges[j+2], e3 = edges[j+3];
            __half2 h0 = Xl[(size_t)e0.x * 64];
            __half2 h1 = Xl[(size_t)e1.x * 64];
            __half2 h2 = Xl[(size_t)e2.x * 64];
            __half2 h3 = Xl[(size_t)e3.x * 64];
            float2 x0 = __half22float2(h0);
            float2 x1 = __half22float2(h1);
            float2 x2 = __half22float2(h2);
            float2 x3 = __half22float2(h3);
            const float v0 = __int_as_float(e0.y), v1 = __int_as_float(e1.y);
            const float v2 = __int_as_float(e2.y), v3 = __int_as_float(e3.y);
            ax += v0 * x0.x + v1 * x1.x + v2 * x2.x + v3 * x3.x;
            ay += v0 * x0.y + v1 * x1.y + v2 * x2.y + v3 * x3.y;
        }
        for (; j < e; j++) {
            int2 ev = edges[j];
            float2 x = __half22float2(Xl[(size_t)ev.x * 64]);
            const float v = __int_as_float(ev.y);
            ax += v * x.x; ay += v * x.y;
        }
        ax += bias[2 * lane];
        ay += bias[2 * lane + 1];
        ax = ax > 0.f ? ax : 0.01f * ax;
        ay = ay > 0.f ? ay : 0.01f * ay;
        float2* dst = (float2*)(out + (size_t)wid * F + 2 * lane);
        *dst = make_float2(ax, ay);
    } else {
        float a = 0.f;
        const __half* Xl = X + lane;                    // row c -> Xl[c * 64]
        int j = s;
        for (; j + 3 < e; j += 4) {
            int2 e0 = edges[j], e1 = edges[j+1], e2 = edges[j+2], e3 = edges[j+3];
            float x0 = __half2float(Xl[(size_t)e0.x * 64]);
            float x1 = __half2float(Xl[(size_t)e1.x * 64]);
            float x2 = __half2float(Xl[(size_t)e2.x * 64]);
            float x3 = __half2float(Xl[(size_t)e3.x * 64]);
            a += __int_as_float(e0.y) * x0 + __int_as_float(e1.y) * x1
               + __int_as_float(e2.y) * x2 + __int_as_float(e3.y) * x3;
        }
        for (; j < e; j++) {
            int2 ev = edges[j];
            a += __int_as_float(ev.y) * __half2float(Xl[(size_t)ev.x * 64]);
        }
        a += bias[lane];
        a = a > 0.f ? a : 0.01f * a;
        out[(size_t)wid * F + lane] = a;
    }
}

// ---------------- MFMA GEMM: C = A@W [+bias] [+C], optional fp16 out -------
// No LDS. A (f32 [M][K], row stride == K) loaded as fragments + cvt to fp16;
// Wt (fp16 col-major [BN][K], <=32KB) is L1-resident. Wave = 64x64 tile.
// mfma_f32_16x16x32_f16: A-frag lane holds row=lane&15, k=(lane>>4)*8+j;
// B-frag lane holds col=lane&15, same k-window; D: col=lane&15, row=(lane>>4)*4+r.
template<int K, int BN, bool BIAS, bool ACCUM, bool HOUT>
__global__ __launch_bounds__(256) void mgemm_k(
    const float* __restrict__ A,
    const __half* __restrict__ Wt,
    const float* __restrict__ bias,
    float* __restrict__ C, int M)
{
    constexpr int BM = (BN == 128) ? 128 : 256;
    constexpr int WN = BN / 64;          // waves along N
    const int t = threadIdx.x;
    const int wid = t >> 6;
    const int lane = t & 63;
    const int wr = wid / WN;
    const int wc = wid - wr * WN;
    const int row0 = blockIdx.x * BM + wr * 64;
    const int col0 = wc * 64;
    const int lrow = lane & 15;
    const int kg = lane >> 4;

    f32x4 acc[4][4];
#pragma unroll
    for (int i = 0; i < 4; i++)
#pragma unroll
        for (int j = 0; j < 4; j++) acc[i][j] = (f32x4){0.f, 0.f, 0.f, 0.f};

    const float* ap[4];
#pragma unroll
    for (int i = 0; i < 4; i++) {
        int r = row0 + i * 16 + lrow;
        r = r < M ? r : M - 1;           // clamp: loads valid, store masked
        ap[i] = A + (size_t)r * K + kg * 8;
    }
    const __half* bp[4];
#pragma unroll
    for (int j = 0; j < 4; j++)
        bp[j] = Wt + (size_t)(col0 + j * 16 + lrow) * K + kg * 8;

#pragma unroll
    for (int k0 = 0; k0 < K; k0 += 32) {
        f16x8 af[4], bf[4];
#pragma unroll
        for (int i = 0; i < 4; i++) {
            const f32x4 lo = *(const f32x4*)(ap[i] + k0);
            const f32x4 hi = *(const f32x4*)(ap[i] + k0 + 4);
            f16x8 v;
            v[0] = (_Float16)lo.x; v[1] = (_Float16)lo.y;
            v[2] = (_Float16)lo.z; v[3] = (_Float16)lo.w;
            v[4] = (_Float16)hi.x; v[5] = (_Float16)hi.y;
            v[6] = (_Float16)hi.z; v[7] = (_Float16)hi.w;
            af[i] = v;
        }
#pragma unroll
        for (int j = 0; j < 4; j++)
            bf[j] = *(const f16x8*)(bp[j] + k0);
#pragma unroll
        for (int i = 0; i < 4; i++)
#pragma unroll
            for (int j = 0; j < 4; j++)
                acc[i][j] = __builtin_amdgcn_mfma_f32_16x16x32_f16(af[i], bf[j], acc[i][j], 0, 0, 0);
    }

#pragma unroll
    for (int i = 0; i < 4; i++) {
#pragma unroll
        for (int r = 0; r < 4; r++) {
            const int row = row0 + i * 16 + kg * 4 + r;
            if (row < M) {
#pragma unroll
                for (int j = 0; j < 4; j++) {
                    const int col = col0 + j * 16 + lrow;
                    float v = acc[i][j][r];
                    if (BIAS) v += bias[col];
                    if (HOUT) {
                        ((__half*)C)[(size_t)row * BN + col] = (__half)v;
                    } else {
                        float* cp = C + (size_t)row * BN + col;
                        if (ACCUM) v += *cp;
                        *cp = v;
                    }
                }
            }
        }
    }
}

// ---------------- semantic attention, block-tiled (LDS-staged) ----------------
template<int D, int H, int NT, int LOGH>
__global__ __launch_bounds__(256) void att2_k(
    const float* __restrict__ g0, const float* __restrict__ g1,
    const float* __restrict__ W1, const float* __restrict__ b1,
    const float* __restrict__ W2, float* __restrict__ eo, int N)
{
    __shared__ float sg0[NT * D];
    __shared__ float sg1[NT * D];
    __shared__ float sW1[D * H];
    __shared__ float sw[2][NT];
    __shared__ float sbeta[2][NT];

    const int t = threadIdx.x;
    const int n0 = blockIdx.x * NT;
    constexpr int D4 = D / 4;

    for (int i = t; i < D * H; i += 256) sW1[i] = W1[i];
    for (int i = t; i < NT * D4; i += 256) {
        const int n = i / D4;
        float4 v0 = make_float4(0.f, 0.f, 0.f, 0.f), v1 = v0;
        if (n0 + n < N) {
            v0 = ((const float4*)(g0 + (size_t)(n0 + n) * D))[i - n * D4];
            v1 = ((const float4*)(g1 + (size_t)(n0 + n) * D))[i - n * D4];
        }
        ((float4*)sg0)[i] = v0;
        ((float4*)sg1)[i] = v1;
    }
    __syncthreads();

    constexpr int NPP = 256 / H;
    constexpr int PASSES = NT / NPP;
    const int j = t & (H - 1);
    const int nsub = t >> LOGH;
    const float b1j = b1[j];
    const float W2j = W2[j];

#pragma unroll
    for (int pass = 0; pass < PASSES; pass++) {
        const int n = pass * NPP + nsub;
#pragma unroll
        for (int p = 0; p < 2; p++) {
            const float* g = (p ? sg1 : sg0) + n * D;
            float s = b1j;
#pragma unroll 8
            for (int k = 0; k < D; k++) s += g[k] * sW1[k * H + j];
            float v = tanhf(s) * W2j;
#pragma unroll
            for (int m = 1; m < H; m <<= 1) v += __shfl_xor(v, m);
            if (j == 0) sw[p][n] = v;
        }
    }
    __syncthreads();
    if (t < NT) {
        const float w0 = sw[0][t], w1 = sw[1][t];
        const float mx = fmaxf(w0, w1);
        const float e0 = expf(w0 - mx), e1 = expf(w1 - mx);
        const float inv = 1.f / (e0 + e1);
        sbeta[0][t] = e0 * inv;
        sbeta[1][t] = e1 * inv;
    }
    __syncthreads();
    for (int i = t; i < NT * D4; i += 256) {
        const int n = i / D4;
        if (n0 + n < N) {
            const float4 a = ((const float4*)sg0)[i];
            const float4 b = ((const float4*)sg1)[i];
            const float c0 = sbeta[0][n], c1 = sbeta[1][n];
            float4 o;
            o.x = c0 * a.x + c1 * b.x;
            o.y = c0 * a.y + c1 * b.y;
            o.z = c0 * a.z + c1 * b.z;
            o.w = c0 * a.w + c1 * b.w;
            ((float4*)(eo + (size_t)(n0 + n) * D))[i - n * D4] = o;
        }
    }
}

// ---------------- launch ----------------
extern "C" void kernel_launch(void* const* d_in, const int* in_sizes, int n_in,
                              void* d_out, int out_size, void* d_ws, size_t ws_size,
                              hipStream_t stream)
{
    const float* feat = (const float*)d_in[0];
    const int*   row_aa = (const int*)d_in[1];
    const int*   col_aa = (const int*)d_in[2];
    const float* val_aa = (const float*)d_in[3];
    const int*   row_ab = (const int*)d_in[4];
    const int*   col_ab = (const int*)d_in[5];
    const float* val_ab = (const float*)d_in[6];
    const int*   row_ba = (const int*)d_in[7];
    const int*   col_ba = (const int*)d_in[8];
    const float* val_ba = (const float*)d_in[9];
    const int*   row_bb = (const int*)d_in[10];
    const int*   col_bb = (const int*)d_in[11];
    const float* val_bb = (const float*)d_in[12];
    const float* W0_aa = (const float*)d_in[13]; const float* b0_aa = (const float*)d_in[14];
    const float* W1_aa = (const float*)d_in[15]; const float* b1_aa = (const float*)d_in[16];
    const float* W0_ab = (const float*)d_in[17]; const float* b0_ab = (const float*)d_in[18];
    const float* W1_ab = (const float*)d_in[19]; const float* b1_ab = (const float*)d_in[20];
    const float* W0_ba = (const float*)d_in[21]; const float* b0_ba = (const float*)d_in[22];
    const float* W1_ba = (const float*)d_in[23]; const float* b1_ba = (const float*)d_in[24];
    const float* W0_bb = (const float*)d_in[25]; const float* b0_bb = (const float*)d_in[26];
    const float* W1_bb = (const float*)d_in[27]; const float* b1_bb = (const float*)d_in[28];
    const float* att0_a_W1 = (const float*)d_in[29];
    const float* att0_a_b1 = (const float*)d_in[30];
    const float* att0_a_W2 = (const float*)d_in[31];
    const float* att1_a_W1 = (const float*)d_in[32];
    const float* att1_a_b1 = (const float*)d_in[33];
    const float* att1_a_W2 = (const float*)d_in[34];
    const float* Wf_a = (const float*)d_in[35]; const float* bf_a = (const float*)d_in[36];
    const float* att0_b_W1 = (const float*)d_in[37];
    const float* att0_b_b1 = (const float*)d_in[38];
    const float* att0_b_W2 = (const float*)d_in[39];
    const float* att1_b_W1 = (const float*)d_in[40];
    const float* att1_b_b1 = (const float*)d_in[41];
    const float* att1_b_W2 = (const float*)d_in[42];
    const float* Wf_b = (const float*)d_in[43]; const float* bf_b = (const float*)d_in[44];

    const int E_r[4] = { in_sizes[1], in_sizes[4], in_sizes[7], in_sizes[10] };
    const int* rows_r[4] = { row_aa, row_ab, row_ba, row_bb };
    const int* cols_r[4] = { col_aa, col_ab, col_ba, col_bb };
    const float* vals_r[4] = { val_aa, val_ab, val_ba, val_bb };

    const size_t RSZ = (size_t)12800000;
    size_t Etot = (size_t)E_r[0] + E_r[1] + E_r[2] + E_r[3];
    size_t need = (3 * RSZ + (size_t)4 * (NROW + 1) + (size_t)4 * NBUK
                   + (size_t)4 * (NBUK + 1) + 2 * Etot + 61456 + 64) * 4;
    if (ws_size < need) return;

    float* ws = (float*)d_ws;
    float* A0 = ws;
    float* A1 = ws + RSZ;
    float* A2 = ws + 2 * RSZ;
    float* A3 = (float*)d_out;            // e1_b lives here until final projection
    int*   rp4    = (int*)(ws + 3 * RSZ);
    int*   gcur4  = rp4 + (size_t)4 * (NROW + 1);
    int*   gbase4 = gcur4 + (size_t)4 * NBUK;
    int2*  edgesS = (int2*)(gbase4 + (size_t)4 * (NBUK + 1));
    __half* wtH   = (__half*)((int*)edgesS + 2 * Etot);   // 122880 halves, 16B-aligned
    int2*  stag   = (int2*)ws;            // staging overlaps A0/A1 (unused during build)

    size_t eoff[4];
    eoff[0] = 0; eoff[1] = eoff[0] + E_r[0];
    eoff[2] = eoff[1] + E_r[1]; eoff[3] = eoff[2] + E_r[2];

    float* out = (float*)d_out;
    const float* fa = feat;
    const float* fb = feat + (size_t)NA * FT;

    const dim3 blk(256);
    const int gM128 = (NROW + 127) / 128;      // mgemm BN=128 grid
    const int gM256 = (NROW + 255) / 256;      // mgemm BN=64 grid
    const int spg = (NROW * 64 + 255) / 256;   // spmm: one wave per row
    const int ag128 = (NROW + 15) / 16;        // att2 D=128, NT=16
    const int ag64  = (NROW + 31) / 32;        // att2 D=64,  NT=32

    // fp16 col-major weight offsets (halves)
    const int o0aa = 0,      o0ab = 16384, o0ba = 32768, o0bb = 49152;
    const int o1aa = 65536,  o1ab = 73728, o1ba = 81920, o1bb = 90112;
    const int ofau = 98304,  ofaf = 102400, ofbu = 110592, ofbf = 114688;

    // ================= weight conversion + CSR build =================
    zero_k<<<(NBUK + 255) / 256, blk, 0, stream>>>((float4*)gcur4, NBUK);  // 4*NBUK ints = NBUK float4
    {
        WJobs jb;
        jb.j[0]  = { W0_aa, 128, 128, o0aa };
        jb.j[1]  = { W0_ab, 128, 128, o0ab };
        jb.j[2]  = { W0_ba, 128, 128, o0ba };
        jb.j[3]  = { W0_bb, 128, 128, o0bb };
        jb.j[4]  = { W1_aa, 128, 64,  o1aa };
        jb.j[5]  = { W1_ab, 128, 64,  o1ab };
        jb.j[6]  = { W1_ba, 128, 64,  o1ba };
        jb.j[7]  = { W1_bb, 128, 64,  o1bb };
        jb.j[8]  = { Wf_a,            64,  64, ofau };
        jb.j[9]  = { Wf_a + 64 * 64,  128, 64, ofaf };
        jb.j[10] = { Wf_b,            64,  64, ofbu };
        jb.j[11] = { Wf_b + 64 * 64,  128, 64, ofbf };
        cvtw_k<<<12, blk, 0, stream>>>(jb, wtH);
    }
    for (int r = 0; r < 4; r++)
        binA_k<<<(E_r[r] + CHUNK - 1) / CHUNK, blk, 0, stream>>>(
            rows_r[r], cols_r[r], vals_r[r], gcur4 + (size_t)r * NBUK,
            stag + (size_t)r * NBUK * BCAP, E_r[r]);
    scanb_k<<<4, blk, 0, stream>>>(gcur4, gbase4, rp4);
    for (int r = 0; r < 4; r++)
        placeB_k<<<NBUK, blk, 0, stream>>>(
            gcur4 + (size_t)r * NBUK, gbase4 + (size_t)r * (NBUK + 1),
            stag + (size_t)r * NBUK * BCAP, edgesS + eoff[r],
            rp4 + (size_t)r * (NROW + 1), NROW);

    const int* rp_aa = rp4;
    const int* rp_ab = rp4 + (NROW + 1);
    const int* rp_ba = rp4 + 2 * (NROW + 1);
    const int* rp_bb = rp4 + 3 * (NROW + 1);
    const int2* es_aa = edgesS + eoff[0];
    const int2* es_ab = edgesS + eoff[1];
    const int2* es_ba = edgesS + eoff[2];
    const int2* es_bb = edgesS + eoff[3];

    const __half* H0 = (const __half*)A0;   // fp16 view of the pre-agg buffer

    // ================= layer 0, type a =================
    mgemm_k<128, 128, false, false, true><<<gM128, blk, 0, stream>>>(fa, wtH + o0aa, nullptr, A0, NA);
    spmm_csr_k<128><<<spg, blk, 0, stream>>>(rp_aa, es_aa, H0, b0_aa, A1, NA);
    mgemm_k<128, 128, false, false, true><<<gM128, blk, 0, stream>>>(fb, wtH + o0ab, nullptr, A0, NB);
    spmm_csr_k<128><<<spg, blk, 0, stream>>>(rp_ab, es_ab, H0, b0_ab, A2, NA);
    att2_k<128, 32, 16, 5><<<ag128, blk, 0, stream>>>(A1, A2, att0_a_W1, att0_a_b1, att0_a_W2, A1, NA);
    // e1_a in A1

    // ================= layer 0, type b =================
    mgemm_k<128, 128, false, false, true><<<gM128, blk, 0, stream>>>(fa, wtH + o0ba, nullptr, A0, NA);
    spmm_csr_k<128><<<spg, blk, 0, stream>>>(rp_ba, es_ba, H0, b0_ba, A3, NB);
    mgemm_k<128, 128, false, false, true><<<gM128, blk, 0, stream>>>(fb, wtH + o0bb, nullptr, A0, NB);
    spmm_csr_k<128><<<spg, blk, 0, stream>>>(rp_bb, es_bb, H0, b0_bb, A2, NB);
    att2_k<128, 32, 16, 5><<<ag128, blk, 0, stream>>>(A3, A2, att0_b_W1, att0_b_b1, att0_b_W2, A3, NB);
    // e1_b in A3 (= d_out region)

    float* A0lo = A0;            float* A0hi = A0 + RSZ / 2;
    float* A2lo = A2;            float* A2hi = A2 + RSZ / 2;
    const __half* H0lo = (const __half*)A0lo;
    const __half* H2lo = (const __half*)A2lo;

    // ================= layer 1, type a =================
    mgemm_k<128, 64, false, false, true><<<gM256, blk, 0, stream>>>(A1, wtH + o1aa, nullptr, A0lo, NA);
    spmm_csr_k<64><<<spg, blk, 0, stream>>>(rp_aa, es_aa, H0lo, b1_aa, A0hi, NA);
    mgemm_k<128, 64, false, false, true><<<gM256, blk, 0, stream>>>(A3, wtH + o1ab, nullptr, A2lo, NB);
    spmm_csr_k<64><<<spg, blk, 0, stream>>>(rp_ab, es_ab, H2lo, b1_ab, A2hi, NA);
    att2_k<64, 16, 32, 4><<<ag64, blk, 0, stream>>>(A0hi, A2hi, att1_a_W1, att1_a_b1, att1_a_W2, A0hi, NA);
    // u_a in A0hi

    // ================= layer 1, type b =================
    mgemm_k<128, 64, false, false, true><<<gM256, blk, 0, stream>>>(A1, wtH + o1ba, nullptr, A2lo, NA);
    spmm_csr_k<64><<<spg, blk, 0, stream>>>(rp_ba, es_ba, H2lo, b1_ba, A2hi, NB);
    mgemm_k<128, 64, false, false, true><<<gM256, blk, 0, stream>>>(A3, wtH + o1bb, nullptr, A2lo, NB);
    spmm_csr_k<64><<<spg, blk, 0, stream>>>(rp_bb, es_bb, H2lo, b1_bb, A0lo, NB);
    att2_k<64, 16, 32, 4><<<ag64, blk, 0, stream>>>(A2hi, A0lo, att1_b_W1, att1_b_b1, att1_b_W2, A2hi, NB);
    // u_b in A2hi

    // ================= final projection =================
    mgemm_k<64,  64, true,  false, false><<<gM256, blk, 0, stream>>>(A0hi, wtH + ofau, bf_a, out, NA);
    mgemm_k<128, 64, false, true,  false><<<gM256, blk, 0, stream>>>(fa, wtH + ofaf, nullptr, out, NA);
    mgemm_k<64,  64, true,  false, false><<<gM256, blk, 0, stream>>>(A2hi, wtH + ofbu, bf_b, out + (size_t)NA * OUTD, NB);
    mgemm_k<128, 64, false, true,  false><<<gM256, blk, 0, stream>>>(fb, wtH + ofbf, nullptr, out + (size_t)NA * OUTD, NB);
}